// Round 2
// baseline (5031.850 us; speedup 1.0000x reference)
//
#include <hip/hip_runtime.h>
#include <math.h>

// ---------------------------------------------------------------------------
// DAGNN: h=relu(nf@W1+b1); logits=h@W2+b2; 20x (x<-A x) with fused gated sum
// out = sum_k sigmoid(x_k . Wg + bg) * x_k    (k=0..20, x_0 = logits)
//
// SpMM locality plan: edges bucketed by key = chunk(sender)*n + receiver,
// chunk(sender) = sender >> 13  (13 chunks of 8192 nodes = 2MB x-slices).
// A fully-resident grid sweeps chunks in lockstep so each phase's gathers hit
// a 2MB slice cached in every XCD's L2 instead of bouncing off the LLC.
// ---------------------------------------------------------------------------

#define F_IN 512
#define C 64        // hidden == n_classes == 64
#define CSHIFT 13   // sender-chunk = sender >> 13  (8192 nodes = 2MB slice)
#define GPW 17      // receiver nodes owned per wave in spmm
#define SE 8192     // elements per block in the 3-pass scan

// ---------- GEMM1: [M,512] @ [512,64] + b1, relu --------------------------
__global__ __launch_bounds__(256) void gemm1_relu(
    const float* __restrict__ A, const float* __restrict__ W1,
    const float* __restrict__ b1, float* __restrict__ H, int M)
{
  __shared__ __align__(16) float As[16][68];  // transposed [k][m], pad to 68
  __shared__ __align__(16) float Bs[16][64];
  int t = threadIdx.x;
  int tx = t & 15, ty = t >> 4;
  int m0 = blockIdx.x * 64;
  int lm = t >> 2, lk = (t & 3) << 2;
  const float* Arow = A + (size_t)(m0 + lm) * F_IN;
  bool aok = (m0 + lm) < M;
  float acc[4][4] = {};

  for (int k0 = 0; k0 < F_IN; k0 += 16) {
    float4 av = make_float4(0.f, 0.f, 0.f, 0.f);
    if (aok) av = *(const float4*)(Arow + k0 + lk);
    float bv[4];
#pragma unroll
    for (int i = 0; i < 4; ++i)
      bv[i] = W1[(size_t)(k0 + (t >> 6) + (i << 2)) * C + (t & 63)];
    __syncthreads();
    As[lk + 0][lm] = av.x; As[lk + 1][lm] = av.y;
    As[lk + 2][lm] = av.z; As[lk + 3][lm] = av.w;
#pragma unroll
    for (int i = 0; i < 4; ++i)
      Bs[(t >> 6) + (i << 2)][t & 63] = bv[i];
    __syncthreads();
#pragma unroll
    for (int kk = 0; kk < 16; ++kk) {
      float4 a = *(const float4*)&As[kk][ty << 2];
      float4 b = *(const float4*)&Bs[kk][tx << 2];
      acc[0][0] += a.x * b.x; acc[0][1] += a.x * b.y; acc[0][2] += a.x * b.z; acc[0][3] += a.x * b.w;
      acc[1][0] += a.y * b.x; acc[1][1] += a.y * b.y; acc[1][2] += a.y * b.z; acc[1][3] += a.y * b.w;
      acc[2][0] += a.z * b.x; acc[2][1] += a.z * b.y; acc[2][2] += a.z * b.z; acc[2][3] += a.z * b.w;
      acc[3][0] += a.w * b.x; acc[3][1] += a.w * b.y; acc[3][2] += a.w * b.z; acc[3][3] += a.w * b.w;
    }
    __syncthreads();
  }
  float4 bb = *(const float4*)&b1[tx << 2];
#pragma unroll
  for (int i = 0; i < 4; ++i) {
    int row = m0 + (ty << 2) + i;
    if (row < M) {
      float4 r;
      r.x = fmaxf(acc[i][0] + bb.x, 0.f);
      r.y = fmaxf(acc[i][1] + bb.y, 0.f);
      r.z = fmaxf(acc[i][2] + bb.z, 0.f);
      r.w = fmaxf(acc[i][3] + bb.w, 0.f);
      *(float4*)&H[(size_t)row * C + (tx << 2)] = r;
    }
  }
}

// ---------- GEMM2 + gate init: logits = h@W2+b2; out = sig(logits.Wg+bg)*logits
__global__ __launch_bounds__(256) void gemm2_gate(
    const float* __restrict__ h, const float* __restrict__ W2,
    const float* __restrict__ b2, const float* __restrict__ Wg,
    const float* __restrict__ bgp, float* __restrict__ logits,
    float* __restrict__ out, int n)
{
  __shared__ float W2s[C * C];
  int t = threadIdx.x;
  for (int i = t; i < C * C; i += blockDim.x) W2s[i] = W2[i];
  __syncthreads();
  int lane = t & 63, wid = t >> 6;
  int wave = blockIdx.x * (blockDim.x >> 6) + wid;
  int nw = gridDim.x * (blockDim.x >> 6);
  float wg = Wg[lane], bgv = bgp[0], b2v = b2[lane];
  for (int node = wave; node < n; node += nw) {
    float hv = h[(size_t)node * C + lane];
    float acc = b2v;
#pragma unroll
    for (int k = 0; k < C; ++k) {
      float hk = __shfl(hv, k, 64);
      acc += hk * W2s[k * C + lane];
    }
    float p = acc * wg;
#pragma unroll
    for (int off = 32; off > 0; off >>= 1) p += __shfl_xor(p, off, 64);
    float g = 1.f / (1.f + expf(-(p + bgv)));
    size_t o = (size_t)node * C + lane;
    logits[o] = acc;
    out[o] = g * acc;
  }
}

// ---------- keyed CSR build -----------------------------------------------
__global__ void zero_int(int* __restrict__ p, int n) {
  int i = blockIdx.x * blockDim.x + threadIdx.x;
  if (i < n) p[i] = 0;
}

__global__ void hist_keys(const int* __restrict__ send, const int* __restrict__ recv,
                          int* __restrict__ cnt, int E, int n) {
  int i = blockIdx.x * blockDim.x + threadIdx.x;
  if (i < E) {
    int key = (send[i] >> CSHIFT) * n + recv[i];
    atomicAdd(&cnt[key], 1);
  }
}

// ---- 3-pass exclusive scan over nkeys (<= 8.4M) ints, in-place -> cursor ----
__global__ __launch_bounds__(1024) void scan_reduce(
    const int* __restrict__ cnt, int* __restrict__ bsum, int nkeys)
{
  int beg = blockIdx.x * SE;
  int end = min(beg + SE, nkeys);
  int v = 0;
  for (int i = beg + threadIdx.x; i < end; i += 1024) v += cnt[i];
#pragma unroll
  for (int off = 32; off > 0; off >>= 1) v += __shfl_xor(v, off, 64);
  __shared__ int ws[16];
  int lane = threadIdx.x & 63, wid = threadIdx.x >> 6;
  if (lane == 0) ws[wid] = v;
  __syncthreads();
  if (threadIdx.x == 0) {
    int s = 0;
#pragma unroll
    for (int i = 0; i < 16; ++i) s += ws[i];
    bsum[blockIdx.x] = s;
  }
}

__global__ __launch_bounds__(1024) void scan_bsum(int* __restrict__ bsum, int nb) {
  int t = threadIdx.x;
  int v = (t < nb) ? bsum[t] : 0;
  int lane = t & 63, wid = t >> 6;
  int incl = v;
#pragma unroll
  for (int off = 1; off < 64; off <<= 1) {
    int u = __shfl_up(incl, off, 64);
    if (lane >= off) incl += u;
  }
  __shared__ int ws[16], wexcl[16];
  if (lane == 63) ws[wid] = incl;
  __syncthreads();
  if (t == 0) {
    int r = 0;
#pragma unroll
    for (int i = 0; i < 16; ++i) { wexcl[i] = r; r += ws[i]; }
  }
  __syncthreads();
  int excl = wexcl[wid] + incl - v;
  if (t < nb) bsum[t] = excl;
}

__global__ __launch_bounds__(1024) void scan_apply(
    int* __restrict__ cnt, const int* __restrict__ bsum, int nkeys)
{
  int t = threadIdx.x;
  int i0 = blockIdx.x * SE + t * 8;
  int loc[8]; int s = 0;
#pragma unroll
  for (int j = 0; j < 8; ++j) {
    int i = i0 + j;
    int v = (i < nkeys) ? cnt[i] : 0;
    loc[j] = v; s += v;
  }
  int lane = t & 63, wid = t >> 6;
  int incl = s;
#pragma unroll
  for (int off = 1; off < 64; off <<= 1) {
    int u = __shfl_up(incl, off, 64);
    if (lane >= off) incl += u;
  }
  __shared__ int ws[16], wexcl[16];
  if (lane == 63) ws[wid] = incl;
  __syncthreads();
  if (t == 0) {
    int r = 0;
#pragma unroll
    for (int i = 0; i < 16; ++i) { wexcl[i] = r; r += ws[i]; }
  }
  __syncthreads();
  int run = bsum[blockIdx.x] + wexcl[wid] + (incl - s);
#pragma unroll
  for (int j = 0; j < 8; ++j) {
    int i = i0 + j;
    if (i < nkeys) cnt[i] = run;
    run += loc[j];
  }
}

// scatter: packed (sender, weight_bits) -> one 8B store per edge.
// After this kernel, cursor[key] == end offset of segment key (inclusive
// prefix), so segment key spans [cursor[key-1], cursor[key]).
__global__ void scatter_edges(
    const int* __restrict__ send, const int* __restrict__ recv,
    const float* __restrict__ ew, int* __restrict__ cursor,
    int2* __restrict__ csr, int E, int n)
{
  int i = blockIdx.x * blockDim.x + threadIdx.x;
  if (i < E) {
    int s = send[i];
    int key = (s >> CSHIFT) * n + recv[i];
    int p = atomicAdd(&cursor[key], 1);
    csr[p] = make_int2(s, __float_as_int(ew[i]));
  }
}

// ---------- chunk-phased SpMM + gate accumulate ----------------------------
// Wave owns GPW receivers; sweeps sender-chunks c=0..nch-1 (all waves roughly
// in lockstep -> phase-c gathers hit the 2MB x-slice in XCD L2).
// Per-node partials live in LDS accs[wave][g][lane]; per-phase edge (s,w)
// staged per-lane and broadcast via readlane so gathers stay independent.
__global__ __launch_bounds__(256, 6) void spmm_gate_chunked(
    const float* __restrict__ x, const int* __restrict__ cursor,
    const int2* __restrict__ csr, const float* __restrict__ Wg,
    const float* __restrict__ bgp, float* __restrict__ x_next,
    float* __restrict__ out, int n, int nch)
{
  __shared__ float accs[4][GPW][64];
  int t = threadIdx.x;
  int lane = t & 63, wid = t >> 6;
  int wave = blockIdx.x * 4 + wid;
  int node0 = wave * GPW;
  if (node0 >= n) return;
  int ng = n - node0; if (ng > GPW) ng = GPW;

  float wg = Wg[lane], bgv = bgp[0];

#pragma unroll
  for (int g = 0; g < GPW; ++g) accs[wid][g][lane] = 0.f;

  for (int c = 0; c < nch; ++c) {
    int K0 = c * n + node0;
    // lane g in [0,ng] holds boundary: start of key K0+g  (== cursor[K0+g-1])
    int idx = K0 + lane - 1;
    int rsv = 0;
    if (lane <= ng && idx >= 0) rsv = cursor[idx];
    int runbeg = __builtin_amdgcn_readlane(rsv, 0);
    int runend = __builtin_amdgcn_readlane(rsv, ng);

    int g = 0;
    int ge = __builtin_amdgcn_readlane(rsv, 1);
    float cura = 0.f;

    for (int base = runbeg; base < runend; base += 64) {
      int2 ev = make_int2(0, 0);
      if (base + lane < runend) ev = csr[base + lane];
      int cnt = runend - base; if (cnt > 64) cnt = 64;
      for (int j = 0; j < cnt; ++j) {
        int e = base + j;
        while (e >= ge) {              // wave-uniform: advance to edge's node
          accs[wid][g][lane] += cura;
          cura = 0.f;
          ++g;
          ge = __builtin_amdgcn_readlane(rsv, g + 1);
        }
        int s = __builtin_amdgcn_readlane(ev.x, j);
        float w = __int_as_float(__builtin_amdgcn_readlane(ev.y, j));
        cura += w * x[(unsigned)(s * C + lane)];
      }
    }
    accs[wid][g][lane] += cura;        // flush tail (0 if run empty)
  }

  // gate + write
  for (int g = 0; g < ng; ++g) {
    float a = accs[wid][g][lane];
    float p = a * wg;
#pragma unroll
    for (int off = 32; off > 0; off >>= 1) p += __shfl_xor(p, off, 64);
    float gt = 1.f / (1.f + expf(-(p + bgv)));
    size_t o = (size_t)(node0 + g) * C + lane;
    x_next[o] = a;
    out[o] += gt * a;
  }
}

// ---------------------------------------------------------------------------
extern "C" void kernel_launch(void* const* d_in, const int* in_sizes, int n_in,
                              void* d_out, int out_size, void* d_ws, size_t ws_size,
                              hipStream_t stream) {
  const float* nf   = (const float*)d_in[0];
  const float* ew   = (const float*)d_in[1];
  const float* W1   = (const float*)d_in[2];
  const float* b1   = (const float*)d_in[3];
  const float* W2   = (const float*)d_in[4];
  const float* b2   = (const float*)d_in[5];
  const float* Wg   = (const float*)d_in[6];
  const float* bg   = (const float*)d_in[7];
  const int* send   = (const int*)d_in[8];
  const int* recv   = (const int*)d_in[9];
  float* out = (float*)d_out;

  int n = in_sizes[0] / F_IN;     // 100000
  int E = in_sizes[1];            // 3200000

  int nch = ((n - 1) >> CSHIFT) + 1;          // 13 for n=100000
  int nkeys = nch * n;                        // 1.3M

  // workspace layout (4B units)
  float* buf0 = (float*)d_ws;                       // n*64: logits / x even
  float* buf1 = buf0 + (size_t)n * C;               // n*64: h, then x odd
  int2*  csr  = (int2*)(buf1 + (size_t)n * C);      // E packed (send, w)
  int*   cursor = (int*)(csr + E);                  // nkeys (hist->scan->cursor)
  int*   bsum = cursor + nkeys;                     // scan block sums (~200)

  // 1) h = relu(nf@W1+b1)  -> buf1
  gemm1_relu<<<(n + 63) / 64, 256, 0, stream>>>(nf, W1, b1, buf1, n);

  // 2) logits = h@W2+b2 -> buf0 ; out = sig(logits.Wg+bg)*logits
  gemm2_gate<<<(n + 3) / 4, 256, 0, stream>>>(buf1, W2, b2, Wg, bg, buf0, out, n);

  // 3) keyed CSR build: key = chunk(sender)*n + receiver
  zero_int<<<(nkeys + 255) / 256, 256, 0, stream>>>(cursor, nkeys);
  hist_keys<<<(E + 255) / 256, 256, 0, stream>>>(send, recv, cursor, E, n);
  int nb = (nkeys + SE - 1) / SE;                   // 159 blocks
  scan_reduce<<<nb, 1024, 0, stream>>>(cursor, bsum, nkeys);
  scan_bsum<<<1, 1024, 0, stream>>>(bsum, nb);
  scan_apply<<<nb, 1024, 0, stream>>>(cursor, bsum, nkeys);
  scatter_edges<<<(E + 255) / 256, 256, 0, stream>>>(send, recv, ew, cursor,
                                                     csr, E, n);

  // 4) 20 propagation hops, gate-fused. x ping-pongs buf0 <-> buf1.
  int nwaves = (n + GPW - 1) / GPW;
  int blocks = (nwaves + 3) / 4;                    // 1471: fully resident @6/CU
  float* xin = buf0;
  float* xout = buf1;
  for (int k = 0; k < 20; ++k) {
    spmm_gate_chunked<<<blocks, 256, 0, stream>>>(xin, cursor, csr, Wg, bg,
                                                  xout, out, n, nch);
    float* tmp = xin; xin = xout; xout = tmp;
  }
}

// Round 3
// 3946.550 us; speedup vs baseline: 1.2750x; 1.2750x over previous
//
#include <hip/hip_runtime.h>
#include <math.h>

// ---------------------------------------------------------------------------
// DAGNN: h=relu(nf@W1+b1); logits=h@W2+b2; 20x (x<-A x) with fused gated sum
// out = sum_k sigmoid(x_k . Wg + bg) * x_k    (k=0..20, x_0 = logits)
//
// SpMM: edges bucketed by key = chunk(sender)*n + receiver (13 chunks of
// 8192 senders = 2MB x-slices). Fully-resident grid sweeps chunks roughly in
// lockstep so phase-c gathers hit the 2MB slice in XCD L2. Inner loop is a
// compile-time-unrolled per-receiver demux (short independent 2-wide loops)
// so gathers retain MLP -- round-2's serial while-advance was the regression.
// ---------------------------------------------------------------------------

#define F_IN 512
#define C 64        // hidden == n_classes == 64
#define CSHIFT 13   // sender-chunk = sender >> 13  (8192 nodes = 2MB slice)
#define GPW 17      // receiver nodes owned per wave in spmm
#define SE 8192     // elements per block in the 3-pass scan

// ---------- GEMM1: [M,512] @ [512,64] + b1, relu --------------------------
__global__ __launch_bounds__(256) void gemm1_relu(
    const float* __restrict__ A, const float* __restrict__ W1,
    const float* __restrict__ b1, float* __restrict__ H, int M)
{
  __shared__ __align__(16) float As[16][68];  // transposed [k][m], pad to 68
  __shared__ __align__(16) float Bs[16][64];
  int t = threadIdx.x;
  int tx = t & 15, ty = t >> 4;
  int m0 = blockIdx.x * 64;
  int lm = t >> 2, lk = (t & 3) << 2;
  const float* Arow = A + (size_t)(m0 + lm) * F_IN;
  bool aok = (m0 + lm) < M;
  float acc[4][4] = {};

  for (int k0 = 0; k0 < F_IN; k0 += 16) {
    float4 av = make_float4(0.f, 0.f, 0.f, 0.f);
    if (aok) av = *(const float4*)(Arow + k0 + lk);
    float bv[4];
#pragma unroll
    for (int i = 0; i < 4; ++i)
      bv[i] = W1[(size_t)(k0 + (t >> 6) + (i << 2)) * C + (t & 63)];
    __syncthreads();
    As[lk + 0][lm] = av.x; As[lk + 1][lm] = av.y;
    As[lk + 2][lm] = av.z; As[lk + 3][lm] = av.w;
#pragma unroll
    for (int i = 0; i < 4; ++i)
      Bs[(t >> 6) + (i << 2)][t & 63] = bv[i];
    __syncthreads();
#pragma unroll
    for (int kk = 0; kk < 16; ++kk) {
      float4 a = *(const float4*)&As[kk][ty << 2];
      float4 b = *(const float4*)&Bs[kk][tx << 2];
      acc[0][0] += a.x * b.x; acc[0][1] += a.x * b.y; acc[0][2] += a.x * b.z; acc[0][3] += a.x * b.w;
      acc[1][0] += a.y * b.x; acc[1][1] += a.y * b.y; acc[1][2] += a.y * b.z; acc[1][3] += a.y * b.w;
      acc[2][0] += a.z * b.x; acc[2][1] += a.z * b.y; acc[2][2] += a.z * b.z; acc[2][3] += a.z * b.w;
      acc[3][0] += a.w * b.x; acc[3][1] += a.w * b.y; acc[3][2] += a.w * b.z; acc[3][3] += a.w * b.w;
    }
    __syncthreads();
  }
  float4 bb = *(const float4*)&b1[tx << 2];
#pragma unroll
  for (int i = 0; i < 4; ++i) {
    int row = m0 + (ty << 2) + i;
    if (row < M) {
      float4 r;
      r.x = fmaxf(acc[i][0] + bb.x, 0.f);
      r.y = fmaxf(acc[i][1] + bb.y, 0.f);
      r.z = fmaxf(acc[i][2] + bb.z, 0.f);
      r.w = fmaxf(acc[i][3] + bb.w, 0.f);
      *(float4*)&H[(size_t)row * C + (tx << 2)] = r;
    }
  }
}

// ---------- GEMM2 + gate init: logits = h@W2+b2; out = sig(logits.Wg+bg)*logits
__global__ __launch_bounds__(256) void gemm2_gate(
    const float* __restrict__ h, const float* __restrict__ W2,
    const float* __restrict__ b2, const float* __restrict__ Wg,
    const float* __restrict__ bgp, float* __restrict__ logits,
    float* __restrict__ out, int n)
{
  __shared__ float W2s[C * C];
  int t = threadIdx.x;
  for (int i = t; i < C * C; i += blockDim.x) W2s[i] = W2[i];
  __syncthreads();
  int lane = t & 63, wid = t >> 6;
  int wave = blockIdx.x * (blockDim.x >> 6) + wid;
  int nw = gridDim.x * (blockDim.x >> 6);
  float wg = Wg[lane], bgv = bgp[0], b2v = b2[lane];
  for (int node = wave; node < n; node += nw) {
    float hv = h[(size_t)node * C + lane];
    float acc = b2v;
#pragma unroll
    for (int k = 0; k < C; ++k) {
      float hk = __shfl(hv, k, 64);
      acc += hk * W2s[k * C + lane];
    }
    float p = acc * wg;
#pragma unroll
    for (int off = 32; off > 0; off >>= 1) p += __shfl_xor(p, off, 64);
    float g = 1.f / (1.f + expf(-(p + bgv)));
    size_t o = (size_t)node * C + lane;
    logits[o] = acc;
    out[o] = g * acc;
  }
}

// ---------- keyed CSR build -----------------------------------------------
__global__ void zero_int(int* __restrict__ p, int n) {
  int i = blockIdx.x * blockDim.x + threadIdx.x;
  if (i < n) p[i] = 0;
}

__global__ void hist_keys(const int* __restrict__ send, const int* __restrict__ recv,
                          int* __restrict__ cnt, int E, int n) {
  int i = blockIdx.x * blockDim.x + threadIdx.x;
  if (i < E) {
    int key = (send[i] >> CSHIFT) * n + recv[i];
    atomicAdd(&cnt[key], 1);
  }
}

// ---- 3-pass exclusive scan over nkeys ints, in-place -> cursor ----
__global__ __launch_bounds__(1024) void scan_reduce(
    const int* __restrict__ cnt, int* __restrict__ bsum, int nkeys)
{
  int beg = blockIdx.x * SE;
  int end = min(beg + SE, nkeys);
  int v = 0;
  for (int i = beg + threadIdx.x; i < end; i += 1024) v += cnt[i];
#pragma unroll
  for (int off = 32; off > 0; off >>= 1) v += __shfl_xor(v, off, 64);
  __shared__ int ws[16];
  int lane = threadIdx.x & 63, wid = threadIdx.x >> 6;
  if (lane == 0) ws[wid] = v;
  __syncthreads();
  if (threadIdx.x == 0) {
    int s = 0;
#pragma unroll
    for (int i = 0; i < 16; ++i) s += ws[i];
    bsum[blockIdx.x] = s;
  }
}

__global__ __launch_bounds__(1024) void scan_bsum(int* __restrict__ bsum, int nb) {
  int t = threadIdx.x;
  int v = (t < nb) ? bsum[t] : 0;
  int lane = t & 63, wid = t >> 6;
  int incl = v;
#pragma unroll
  for (int off = 1; off < 64; off <<= 1) {
    int u = __shfl_up(incl, off, 64);
    if (lane >= off) incl += u;
  }
  __shared__ int ws[16], wexcl[16];
  if (lane == 63) ws[wid] = incl;
  __syncthreads();
  if (t == 0) {
    int r = 0;
#pragma unroll
    for (int i = 0; i < 16; ++i) { wexcl[i] = r; r += ws[i]; }
  }
  __syncthreads();
  int excl = wexcl[wid] + incl - v;
  if (t < nb) bsum[t] = excl;
}

__global__ __launch_bounds__(1024) void scan_apply(
    int* __restrict__ cnt, const int* __restrict__ bsum, int nkeys)
{
  int t = threadIdx.x;
  int i0 = blockIdx.x * SE + t * 8;
  int loc[8]; int s = 0;
#pragma unroll
  for (int j = 0; j < 8; ++j) {
    int i = i0 + j;
    int v = (i < nkeys) ? cnt[i] : 0;
    loc[j] = v; s += v;
  }
  int lane = t & 63, wid = t >> 6;
  int incl = s;
#pragma unroll
  for (int off = 1; off < 64; off <<= 1) {
    int u = __shfl_up(incl, off, 64);
    if (lane >= off) incl += u;
  }
  __shared__ int ws[16], wexcl[16];
  if (lane == 63) ws[wid] = incl;
  __syncthreads();
  if (t == 0) {
    int r = 0;
#pragma unroll
    for (int i = 0; i < 16; ++i) { wexcl[i] = r; r += ws[i]; }
  }
  __syncthreads();
  int run = bsum[blockIdx.x] + wexcl[wid] + (incl - s);
#pragma unroll
  for (int j = 0; j < 8; ++j) {
    int i = i0 + j;
    if (i < nkeys) cnt[i] = run;
    run += loc[j];
  }
}

// scatter: packed (sender, weight_bits) -> one 8B store per edge.
// After this kernel, cursor[key] == inclusive prefix (end of segment key),
// so segment key spans [cursor[key-1], cursor[key]).
__global__ void scatter_edges(
    const int* __restrict__ send, const int* __restrict__ recv,
    const float* __restrict__ ew, int* __restrict__ cursor,
    int2* __restrict__ csr, int E, int n)
{
  int i = blockIdx.x * blockDim.x + threadIdx.x;
  if (i < E) {
    int s = send[i];
    int key = (s >> CSHIFT) * n + recv[i];
    int p = atomicAdd(&cursor[key], 1);
    csr[p] = make_int2(s, __float_as_int(ew[i]));
  }
}

// ---------- chunk-phased SpMM + gate accumulate ----------------------------
// Wave owns GPW receivers; sweeps sender-chunks c=0..nch-1. Per chunk: stage
// a 64-edge batch, then compile-time-unrolled per-receiver demux: receiver g's
// sub-range is [readlane(rsv,g), readlane(rsv,g+1)) clamped to the batch.
// All indices are wave-uniform -> per edge: 2 readlane + SGPR-based gather +
// fma; the 17 unrolled bodies hit independent accumulators -> MLP preserved.
__global__ __launch_bounds__(256, 6) void spmm_gate_chunked(
    const float* __restrict__ x, const int* __restrict__ cursor,
    const int2* __restrict__ csr, const float* __restrict__ Wg,
    const float* __restrict__ bgp, float* __restrict__ x_next,
    float* __restrict__ out, int n, int nch)
{
  __shared__ float accs[4][GPW][64];
  int t = threadIdx.x;
  int lane = t & 63, wid = t >> 6;
  int wave = blockIdx.x * 4 + wid;
  int node0 = wave * GPW;
  bool active = node0 < n;
  int ng = 0;
  if (active) { ng = n - node0; if (ng > GPW) ng = GPW; }

  float wg = Wg[lane], bgv = bgp[0];

#pragma unroll
  for (int g = 0; g < GPW; ++g) accs[wid][g][lane] = 0.f;

  for (int c = 0; c < nch; ++c) {
    if (active) {
      int K0 = c * n + node0;
      // lane g in [0,ng] holds boundary: start of key K0+g (== cursor[K0+g-1])
      int idx = K0 + lane - 1;
      int rsv = 0;
      if (lane <= ng && idx >= 0) rsv = cursor[idx];
      int runbeg = __builtin_amdgcn_readlane(rsv, 0);
      int runend = __builtin_amdgcn_readlane(rsv, ng);

      for (int base = runbeg; base < runend; base += 64) {
        int2 ev = make_int2(0, 0);
        if (base + lane < runend) ev = csr[base + lane];
        int hi = base + 64; if (hi > runend) hi = runend;
#pragma unroll
        for (int g = 0; g < GPW; ++g) {
          if (g < ng) {
            int b = __builtin_amdgcn_readlane(rsv, g);      // seg start (abs)
            int e = __builtin_amdgcn_readlane(rsv, g + 1);  // seg end   (abs)
            int jb = (b > base) ? b : base;
            int je = (e < hi) ? e : hi;
            if (jb < je) {
              float a0 = 0.f, a1 = 0.f;
              int j = jb - base, jn = je - base;
              for (; j + 2 <= jn; j += 2) {
                int s0 = __builtin_amdgcn_readlane(ev.x, j);
                int s1 = __builtin_amdgcn_readlane(ev.x, j + 1);
                float w0 = __int_as_float(__builtin_amdgcn_readlane(ev.y, j));
                float w1 = __int_as_float(__builtin_amdgcn_readlane(ev.y, j + 1));
                a0 += w0 * x[(unsigned)(s0 * C) + lane];
                a1 += w1 * x[(unsigned)(s1 * C) + lane];
              }
              if (j < jn) {
                int s0 = __builtin_amdgcn_readlane(ev.x, j);
                float w0 = __int_as_float(__builtin_amdgcn_readlane(ev.y, j));
                a0 += w0 * x[(unsigned)(s0 * C) + lane];
              }
              accs[wid][g][lane] += a0 + a1;
            }
          }
        }
      }
    }
    __syncthreads();   // keep block's 4 waves phase-aligned (all waves reach)
  }

  // gate + write
  for (int g = 0; g < ng; ++g) {
    float a = accs[wid][g][lane];
    float p = a * wg;
#pragma unroll
    for (int off = 32; off > 0; off >>= 1) p += __shfl_xor(p, off, 64);
    float gt = 1.f / (1.f + expf(-(p + bgv)));
    size_t o = (size_t)(node0 + g) * C + lane;
    x_next[o] = a;
    out[o] += gt * a;
  }
}

// ---------------------------------------------------------------------------
extern "C" void kernel_launch(void* const* d_in, const int* in_sizes, int n_in,
                              void* d_out, int out_size, void* d_ws, size_t ws_size,
                              hipStream_t stream) {
  const float* nf   = (const float*)d_in[0];
  const float* ew   = (const float*)d_in[1];
  const float* W1   = (const float*)d_in[2];
  const float* b1   = (const float*)d_in[3];
  const float* W2   = (const float*)d_in[4];
  const float* b2   = (const float*)d_in[5];
  const float* Wg   = (const float*)d_in[6];
  const float* bg   = (const float*)d_in[7];
  const int* send   = (const int*)d_in[8];
  const int* recv   = (const int*)d_in[9];
  float* out = (float*)d_out;

  int n = in_sizes[0] / F_IN;     // 100000
  int E = in_sizes[1];            // 3200000

  int nch = ((n - 1) >> CSHIFT) + 1;          // 13 for n=100000
  int nkeys = nch * n;                        // 1.3M

  // workspace layout (4B units)
  float* buf0 = (float*)d_ws;                       // n*64: logits / x even
  float* buf1 = buf0 + (size_t)n * C;               // n*64: h, then x odd
  int2*  csr  = (int2*)(buf1 + (size_t)n * C);      // E packed (send, w)
  int*   cursor = (int*)(csr + E);                  // nkeys (hist->scan->cursor)
  int*   bsum = cursor + nkeys;                     // scan block sums (~200)

  // 1) h = relu(nf@W1+b1)  -> buf1
  gemm1_relu<<<(n + 63) / 64, 256, 0, stream>>>(nf, W1, b1, buf1, n);

  // 2) logits = h@W2+b2 -> buf0 ; out = sig(logits.Wg+bg)*logits
  gemm2_gate<<<(n + 3) / 4, 256, 0, stream>>>(buf1, W2, b2, Wg, bg, buf0, out, n);

  // 3) keyed CSR build: key = chunk(sender)*n + receiver
  zero_int<<<(nkeys + 255) / 256, 256, 0, stream>>>(cursor, nkeys);
  hist_keys<<<(E + 255) / 256, 256, 0, stream>>>(send, recv, cursor, E, n);
  int nb = (nkeys + SE - 1) / SE;                   // 159 blocks
  scan_reduce<<<nb, 1024, 0, stream>>>(cursor, bsum, nkeys);
  scan_bsum<<<1, 1024, 0, stream>>>(bsum, nb);
  scan_apply<<<nb, 1024, 0, stream>>>(cursor, bsum, nkeys);
  scatter_edges<<<(E + 255) / 256, 256, 0, stream>>>(send, recv, ew, cursor,
                                                     csr, E, n);

  // 4) 20 propagation hops, gate-fused. x ping-pongs buf0 <-> buf1.
  int nwaves = (n + GPW - 1) / GPW;
  int blocks = (nwaves + 3) / 4;                    // 1471: fully resident @6/CU
  float* xin = buf0;
  float* xout = buf1;
  for (int k = 0; k < 20; ++k) {
    spmm_gate_chunked<<<blocks, 256, 0, stream>>>(xin, cursor, csr, Wg, bg,
                                                  xout, out, n, nch);
    float* tmp = xin; xin = xout; xout = tmp;
  }
}

// Round 4
// 3152.504 us; speedup vs baseline: 1.5961x; 1.2519x over previous
//
#include <hip/hip_runtime.h>
#include <math.h>

// ---------------------------------------------------------------------------
// DAGNN: h=relu(nf@W1+b1); logits=h@W2+b2; 20x (x<-A x) with fused gated sum
// out = sum_k sigmoid(x_k . Wg + bg) * x_k    (k=0..20, x_0 = logits)
// A x = segment_sum(ew[:,None] * x[senders], receivers) -> receiver-CSR.
//
// Round-4 consolidation: round-0's proven SpMM structure (wave per receiver,
// grid-stride, shfl-broadcast edges -- measured ~7.1 TB/s effective LLC BW)
// + packed int2 CSR (one 8B store/edge: WRITE_SIZE 292->204 MB, measured)
// + plain receiver keys (CSR build over n=100k not 1.3M keys)
// + 8-wide gather ILP in the inner loop.
// Chunk-phased L2 locality dropped: two clean tests showed no benefit.
// ---------------------------------------------------------------------------

#define F_IN 512
#define C 64  // hidden == n_classes == 64

// ---------- GEMM1: [M,512] @ [512,64] + b1, relu --------------------------
__global__ __launch_bounds__(256) void gemm1_relu(
    const float* __restrict__ A, const float* __restrict__ W1,
    const float* __restrict__ b1, float* __restrict__ H, int M)
{
  __shared__ __align__(16) float As[16][68];  // transposed [k][m], pad to 68
  __shared__ __align__(16) float Bs[16][64];
  int t = threadIdx.x;
  int tx = t & 15, ty = t >> 4;
  int m0 = blockIdx.x * 64;
  int lm = t >> 2, lk = (t & 3) << 2;
  const float* Arow = A + (size_t)(m0 + lm) * F_IN;
  bool aok = (m0 + lm) < M;
  float acc[4][4] = {};

  for (int k0 = 0; k0 < F_IN; k0 += 16) {
    float4 av = make_float4(0.f, 0.f, 0.f, 0.f);
    if (aok) av = *(const float4*)(Arow + k0 + lk);
    float bv[4];
#pragma unroll
    for (int i = 0; i < 4; ++i)
      bv[i] = W1[(size_t)(k0 + (t >> 6) + (i << 2)) * C + (t & 63)];
    __syncthreads();
    As[lk + 0][lm] = av.x; As[lk + 1][lm] = av.y;
    As[lk + 2][lm] = av.z; As[lk + 3][lm] = av.w;
#pragma unroll
    for (int i = 0; i < 4; ++i)
      Bs[(t >> 6) + (i << 2)][t & 63] = bv[i];
    __syncthreads();
#pragma unroll
    for (int kk = 0; kk < 16; ++kk) {
      float4 a = *(const float4*)&As[kk][ty << 2];
      float4 b = *(const float4*)&Bs[kk][tx << 2];
      acc[0][0] += a.x * b.x; acc[0][1] += a.x * b.y; acc[0][2] += a.x * b.z; acc[0][3] += a.x * b.w;
      acc[1][0] += a.y * b.x; acc[1][1] += a.y * b.y; acc[1][2] += a.y * b.z; acc[1][3] += a.y * b.w;
      acc[2][0] += a.z * b.x; acc[2][1] += a.z * b.y; acc[2][2] += a.z * b.z; acc[2][3] += a.z * b.w;
      acc[3][0] += a.w * b.x; acc[3][1] += a.w * b.y; acc[3][2] += a.w * b.z; acc[3][3] += a.w * b.w;
    }
    __syncthreads();
  }
  float4 bb = *(const float4*)&b1[tx << 2];
#pragma unroll
  for (int i = 0; i < 4; ++i) {
    int row = m0 + (ty << 2) + i;
    if (row < M) {
      float4 r;
      r.x = fmaxf(acc[i][0] + bb.x, 0.f);
      r.y = fmaxf(acc[i][1] + bb.y, 0.f);
      r.z = fmaxf(acc[i][2] + bb.z, 0.f);
      r.w = fmaxf(acc[i][3] + bb.w, 0.f);
      *(float4*)&H[(size_t)row * C + (tx << 2)] = r;
    }
  }
}

// ---------- GEMM2 + gate init: logits = h@W2+b2; out = sig(logits.Wg+bg)*logits
__global__ __launch_bounds__(256) void gemm2_gate(
    const float* __restrict__ h, const float* __restrict__ W2,
    const float* __restrict__ b2, const float* __restrict__ Wg,
    const float* __restrict__ bgp, float* __restrict__ logits,
    float* __restrict__ out, int n)
{
  __shared__ float W2s[C * C];
  int t = threadIdx.x;
  for (int i = t; i < C * C; i += blockDim.x) W2s[i] = W2[i];
  __syncthreads();
  int lane = t & 63, wid = t >> 6;
  int wave = blockIdx.x * (blockDim.x >> 6) + wid;
  int nw = gridDim.x * (blockDim.x >> 6);
  float wg = Wg[lane], bgv = bgp[0], b2v = b2[lane];
  for (int node = wave; node < n; node += nw) {
    float hv = h[(size_t)node * C + lane];
    float acc = b2v;
#pragma unroll
    for (int k = 0; k < C; ++k) {
      float hk = __shfl(hv, k, 64);
      acc += hk * W2s[k * C + lane];
    }
    float p = acc * wg;
#pragma unroll
    for (int off = 32; off > 0; off >>= 1) p += __shfl_xor(p, off, 64);
    float g = 1.f / (1.f + expf(-(p + bgv)));
    size_t o = (size_t)node * C + lane;
    logits[o] = acc;
    out[o] = g * acc;
  }
}

// ---------- CSR build (receiver-major) ------------------------------------
__global__ void zero_int(int* __restrict__ p, int n) {
  int i = blockIdx.x * blockDim.x + threadIdx.x;
  if (i < n) p[i] = 0;
}

__global__ void hist_recv(const int* __restrict__ recv, int* __restrict__ cnt, int E) {
  int i = blockIdx.x * blockDim.x + threadIdx.x;
  if (i < E) atomicAdd(&cnt[recv[i]], 1);
}

// single-block exclusive scan; writes row_start[0..n] and cursor (aliases cnt)
__global__ __launch_bounds__(1024) void scan_counts(
    int* __restrict__ cnt_cursor, int* __restrict__ row_start, int n)
{
  __shared__ int wsum[16];
  int t = threadIdx.x, lane = t & 63, wid = t >> 6;
  int carry = 0;
  for (int base = 0; base < n; base += 1024) {
    int idx = base + t;
    int v = (idx < n) ? cnt_cursor[idx] : 0;
    int incl = v;
#pragma unroll
    for (int off = 1; off < 64; off <<= 1) {
      int u = __shfl_up(incl, off, 64);
      if (lane >= off) incl += u;
    }
    if (lane == 63) wsum[wid] = incl;
    __syncthreads();
    if (t < 16) {
      int ws = wsum[t];
#pragma unroll
      for (int off = 1; off < 16; off <<= 1) {
        int u = __shfl_up(ws, off, 16);
        if ((t & 15) >= off) ws += u;
      }
      wsum[t] = ws;
    }
    __syncthreads();
    int woff = (wid > 0) ? wsum[wid - 1] : 0;
    int total = wsum[15];
    int excl = carry + woff + (incl - v);
    if (idx < n) { row_start[idx] = excl; cnt_cursor[idx] = excl; }
    carry += total;
    __syncthreads();
  }
  if (t == 0) row_start[n] = carry;
}

// scatter: packed (sender, weight_bits) -> ONE 8B store per edge (1 dirty
// line/edge; measured WRITE_SIZE 292->204 MB vs separate cs/cw arrays).
__global__ void scatter_edges(
    const int* __restrict__ send, const int* __restrict__ recv,
    const float* __restrict__ ew, int* __restrict__ cursor,
    int2* __restrict__ csr, int E)
{
  int i = blockIdx.x * blockDim.x + threadIdx.x;
  if (i < E) {
    int r = recv[i];
    int p = atomicAdd(&cursor[r], 1);
    csr[p] = make_int2(send[i], __float_as_int(ew[i]));
  }
}

// ---------- fused SpMM + gate accumulate ----------------------------------
// wave per receiver node, lane = channel. x_next[r] = sum_e w_e x[s_e];
// out[r] += sigmoid(x_next[r].Wg + bg) * x_next[r].  8-wide gather ILP.
__global__ __launch_bounds__(256) void spmm_gate(
    const float* __restrict__ x, const int* __restrict__ row_start,
    const int2* __restrict__ csr, const float* __restrict__ Wg,
    const float* __restrict__ bgp, float* __restrict__ x_next,
    float* __restrict__ out, int n)
{
  int t = threadIdx.x;
  int lane = t & 63, wid = t >> 6;
  int wave = blockIdx.x * (blockDim.x >> 6) + wid;
  int nw = gridDim.x * (blockDim.x >> 6);
  float wg = Wg[lane], bgv = bgp[0];

  for (int node = wave; node < n; node += nw) {
    int beg = row_start[node], end = row_start[node + 1];
    float a0 = 0.f, a1 = 0.f, a2 = 0.f, a3 = 0.f;
    float a4 = 0.f, a5 = 0.f, a6 = 0.f, a7 = 0.f;
    for (int base = beg; base < end; base += 64) {
      int2 ev = make_int2(0, 0);
      if (base + lane < end) ev = csr[base + lane];
      int cnt = end - base; if (cnt > 64) cnt = 64;
      int j = 0;
      for (; j + 8 <= cnt; j += 8) {
        int   s0 = __shfl(ev.x, j + 0, 64), s1 = __shfl(ev.x, j + 1, 64);
        int   s2 = __shfl(ev.x, j + 2, 64), s3 = __shfl(ev.x, j + 3, 64);
        int   s4 = __shfl(ev.x, j + 4, 64), s5 = __shfl(ev.x, j + 5, 64);
        int   s6 = __shfl(ev.x, j + 6, 64), s7 = __shfl(ev.x, j + 7, 64);
        float w0 = __int_as_float(__shfl(ev.y, j + 0, 64));
        float w1 = __int_as_float(__shfl(ev.y, j + 1, 64));
        float w2 = __int_as_float(__shfl(ev.y, j + 2, 64));
        float w3 = __int_as_float(__shfl(ev.y, j + 3, 64));
        float w4 = __int_as_float(__shfl(ev.y, j + 4, 64));
        float w5 = __int_as_float(__shfl(ev.y, j + 5, 64));
        float w6 = __int_as_float(__shfl(ev.y, j + 6, 64));
        float w7 = __int_as_float(__shfl(ev.y, j + 7, 64));
        float v0 = x[(unsigned)(s0 * C) + lane];
        float v1 = x[(unsigned)(s1 * C) + lane];
        float v2 = x[(unsigned)(s2 * C) + lane];
        float v3 = x[(unsigned)(s3 * C) + lane];
        float v4 = x[(unsigned)(s4 * C) + lane];
        float v5 = x[(unsigned)(s5 * C) + lane];
        float v6 = x[(unsigned)(s6 * C) + lane];
        float v7 = x[(unsigned)(s7 * C) + lane];
        a0 += w0 * v0; a1 += w1 * v1; a2 += w2 * v2; a3 += w3 * v3;
        a4 += w4 * v4; a5 += w5 * v5; a6 += w6 * v6; a7 += w7 * v7;
      }
      for (; j < cnt; ++j) {
        int sj = __shfl(ev.x, j, 64);
        float wj = __int_as_float(__shfl(ev.y, j, 64));
        a0 += wj * x[(unsigned)(sj * C) + lane];
      }
    }
    float acc = ((a0 + a1) + (a2 + a3)) + ((a4 + a5) + (a6 + a7));
    float p = acc * wg;
#pragma unroll
    for (int off = 32; off > 0; off >>= 1) p += __shfl_xor(p, off, 64);
    float g = 1.f / (1.f + expf(-(p + bgv)));
    size_t o = (size_t)node * C + lane;
    x_next[o] = acc;
    out[o] += g * acc;
  }
}

// ---------------------------------------------------------------------------
extern "C" void kernel_launch(void* const* d_in, const int* in_sizes, int n_in,
                              void* d_out, int out_size, void* d_ws, size_t ws_size,
                              hipStream_t stream) {
  const float* nf   = (const float*)d_in[0];
  const float* ew   = (const float*)d_in[1];
  const float* W1   = (const float*)d_in[2];
  const float* b1   = (const float*)d_in[3];
  const float* W2   = (const float*)d_in[4];
  const float* b2   = (const float*)d_in[5];
  const float* Wg   = (const float*)d_in[6];
  const float* bg   = (const float*)d_in[7];
  const int* send   = (const int*)d_in[8];
  const int* recv   = (const int*)d_in[9];
  float* out = (float*)d_out;

  int n = in_sizes[0] / F_IN;     // 100000
  int E = in_sizes[1];            // 3200000

  // workspace layout (4B units)
  float* buf0 = (float*)d_ws;                       // n*64: logits / x even
  float* buf1 = buf0 + (size_t)n * C;               // n*64: h, then x odd
  int2*  csr  = (int2*)(buf1 + (size_t)n * C);      // E packed (send, w)
  int*   row_start = (int*)(csr + E);               // n+1
  int*   cursor = row_start + (n + 1);              // n (histogram -> cursor)

  // 1) h = relu(nf@W1+b1)  -> buf1
  gemm1_relu<<<(n + 63) / 64, 256, 0, stream>>>(nf, W1, b1, buf1, n);

  // 2) logits = h@W2+b2 -> buf0 ; out = sig(logits.Wg+bg)*logits
  gemm2_gate<<<(n + 3) / 4, 256, 0, stream>>>(buf1, W2, b2, Wg, bg, buf0, out, n);

  // 3) CSR build (receiver-major, packed int2)
  zero_int<<<(n + 255) / 256, 256, 0, stream>>>(cursor, n);
  hist_recv<<<(E + 255) / 256, 256, 0, stream>>>(recv, cursor, E);
  scan_counts<<<1, 1024, 0, stream>>>(cursor, row_start, n);
  scatter_edges<<<(E + 255) / 256, 256, 0, stream>>>(send, recv, ew, cursor,
                                                     csr, E);

  // 4) 20 propagation hops, gate-fused. x ping-pongs buf0 <-> buf1.
  float* xin = buf0;
  float* xout = buf1;
  for (int k = 0; k < 20; ++k) {
    spmm_gate<<<(n + 3) / 4, 256, 0, stream>>>(xin, row_start, csr, Wg, bg,
                                               xout, out, n);
    float* tmp = xin; xin = xout; xout = tmp;
  }
}

// Round 5
// 2499.180 us; speedup vs baseline: 2.0134x; 1.2614x over previous
//
#include <hip/hip_runtime.h>
#include <math.h>

// ---------------------------------------------------------------------------
// DAGNN: h=relu(nf@W1+b1); logits=h@W2+b2; 20x (x<-A x) with fused gated sum
// out = sum_k sigmoid(x_k . Wg + bg) * x_k    (k=0..20, x_0 = logits)
// A x = segment_sum(ew[:,None] * x[senders], receivers) -> receiver-CSR.
//
// Round-5: x stored as fp16 with per-hop 1/16 rescale (scale 16^k tracked as
// exact-fp32 kernel arg). Halves the dominant gather traffic (819->410 MB/hop,
// measured 7.0 TB/s BW-bound at fp32). Gate/out math reconstructs true scale
// in fp32. Rounding: 2^-12 per store, ~0.1% relative after 20 hops.
// Structure otherwise identical to round-4's 3153 us kernel (wave/receiver,
// shfl-broadcast edges, 8-wide gather ILP, packed int2 CSR).
// ---------------------------------------------------------------------------

#define F_IN 512
#define C 64  // hidden == n_classes == 64

__device__ inline float h2f(ushort u) {
  _Float16 h; __builtin_memcpy(&h, &u, 2); return (float)h;
}
__device__ inline ushort f2h(float f) {
  _Float16 h = (_Float16)f; ushort u; __builtin_memcpy(&u, &h, 2); return u;
}

// ---------- GEMM1: [M,512] @ [512,64] + b1, relu --------------------------
__global__ __launch_bounds__(256) void gemm1_relu(
    const float* __restrict__ A, const float* __restrict__ W1,
    const float* __restrict__ b1, float* __restrict__ H, int M)
{
  __shared__ __align__(16) float As[16][68];  // transposed [k][m], pad to 68
  __shared__ __align__(16) float Bs[16][64];
  int t = threadIdx.x;
  int tx = t & 15, ty = t >> 4;
  int m0 = blockIdx.x * 64;
  int lm = t >> 2, lk = (t & 3) << 2;
  const float* Arow = A + (size_t)(m0 + lm) * F_IN;
  bool aok = (m0 + lm) < M;
  float acc[4][4] = {};

  for (int k0 = 0; k0 < F_IN; k0 += 16) {
    float4 av = make_float4(0.f, 0.f, 0.f, 0.f);
    if (aok) av = *(const float4*)(Arow + k0 + lk);
    float bv[4];
#pragma unroll
    for (int i = 0; i < 4; ++i)
      bv[i] = W1[(size_t)(k0 + (t >> 6) + (i << 2)) * C + (t & 63)];
    __syncthreads();
    As[lk + 0][lm] = av.x; As[lk + 1][lm] = av.y;
    As[lk + 2][lm] = av.z; As[lk + 3][lm] = av.w;
#pragma unroll
    for (int i = 0; i < 4; ++i)
      Bs[(t >> 6) + (i << 2)][t & 63] = bv[i];
    __syncthreads();
#pragma unroll
    for (int kk = 0; kk < 16; ++kk) {
      float4 a = *(const float4*)&As[kk][ty << 2];
      float4 b = *(const float4*)&Bs[kk][tx << 2];
      acc[0][0] += a.x * b.x; acc[0][1] += a.x * b.y; acc[0][2] += a.x * b.z; acc[0][3] += a.x * b.w;
      acc[1][0] += a.y * b.x; acc[1][1] += a.y * b.y; acc[1][2] += a.y * b.z; acc[1][3] += a.y * b.w;
      acc[2][0] += a.z * b.x; acc[2][1] += a.z * b.y; acc[2][2] += a.z * b.z; acc[2][3] += a.z * b.w;
      acc[3][0] += a.w * b.x; acc[3][1] += a.w * b.y; acc[3][2] += a.w * b.z; acc[3][3] += a.w * b.w;
    }
    __syncthreads();
  }
  float4 bb = *(const float4*)&b1[tx << 2];
#pragma unroll
  for (int i = 0; i < 4; ++i) {
    int row = m0 + (ty << 2) + i;
    if (row < M) {
      float4 r;
      r.x = fmaxf(acc[i][0] + bb.x, 0.f);
      r.y = fmaxf(acc[i][1] + bb.y, 0.f);
      r.z = fmaxf(acc[i][2] + bb.z, 0.f);
      r.w = fmaxf(acc[i][3] + bb.w, 0.f);
      *(float4*)&H[(size_t)row * C + (tx << 2)] = r;
    }
  }
}

// ---------- GEMM2 + gate init: logits = h@W2+b2 (fp32 math);
// x0 = fp16(logits); out = sig(logits.Wg+bg)*logits
__global__ __launch_bounds__(256) void gemm2_gate(
    const float* __restrict__ h, const float* __restrict__ W2,
    const float* __restrict__ b2, const float* __restrict__ Wg,
    const float* __restrict__ bgp, ushort* __restrict__ x0,
    float* __restrict__ out, int n)
{
  __shared__ float W2s[C * C];
  int t = threadIdx.x;
  for (int i = t; i < C * C; i += blockDim.x) W2s[i] = W2[i];
  __syncthreads();
  int lane = t & 63, wid = t >> 6;
  int wave = blockIdx.x * (blockDim.x >> 6) + wid;
  int nw = gridDim.x * (blockDim.x >> 6);
  float wg = Wg[lane], bgv = bgp[0], b2v = b2[lane];
  for (int node = wave; node < n; node += nw) {
    float hv = h[(size_t)node * C + lane];
    float acc = b2v;
#pragma unroll
    for (int k = 0; k < C; ++k) {
      float hk = __shfl(hv, k, 64);
      acc += hk * W2s[k * C + lane];
    }
    float p = acc * wg;
#pragma unroll
    for (int off = 32; off > 0; off >>= 1) p += __shfl_xor(p, off, 64);
    float g = 1.f / (1.f + expf(-(p + bgv)));
    size_t o = (size_t)node * C + lane;
    x0[o] = f2h(acc);
    out[o] = g * acc;
  }
}

// ---------- CSR build (receiver-major) ------------------------------------
__global__ void zero_int(int* __restrict__ p, int n) {
  int i = blockIdx.x * blockDim.x + threadIdx.x;
  if (i < n) p[i] = 0;
}

__global__ void hist_recv(const int* __restrict__ recv, int* __restrict__ cnt, int E) {
  int i = blockIdx.x * blockDim.x + threadIdx.x;
  if (i < E) atomicAdd(&cnt[recv[i]], 1);
}

// single-block exclusive scan; writes row_start[0..n] and cursor (aliases cnt)
__global__ __launch_bounds__(1024) void scan_counts(
    int* __restrict__ cnt_cursor, int* __restrict__ row_start, int n)
{
  __shared__ int wsum[16];
  int t = threadIdx.x, lane = t & 63, wid = t >> 6;
  int carry = 0;
  for (int base = 0; base < n; base += 1024) {
    int idx = base + t;
    int v = (idx < n) ? cnt_cursor[idx] : 0;
    int incl = v;
#pragma unroll
    for (int off = 1; off < 64; off <<= 1) {
      int u = __shfl_up(incl, off, 64);
      if (lane >= off) incl += u;
    }
    if (lane == 63) wsum[wid] = incl;
    __syncthreads();
    if (t < 16) {
      int ws = wsum[t];
#pragma unroll
      for (int off = 1; off < 16; off <<= 1) {
        int u = __shfl_up(ws, off, 16);
        if ((t & 15) >= off) ws += u;
      }
      wsum[t] = ws;
    }
    __syncthreads();
    int woff = (wid > 0) ? wsum[wid - 1] : 0;
    int total = wsum[15];
    int excl = carry + woff + (incl - v);
    if (idx < n) { row_start[idx] = excl; cnt_cursor[idx] = excl; }
    carry += total;
    __syncthreads();
  }
  if (t == 0) row_start[n] = carry;
}

// scatter: packed (sender, weight_bits) -> ONE 8B store per edge (1 dirty
// line/edge; measured WRITE_SIZE 292->198 MB vs separate arrays).
__global__ void scatter_edges(
    const int* __restrict__ send, const int* __restrict__ recv,
    const float* __restrict__ ew, int* __restrict__ cursor,
    int2* __restrict__ csr, int E)
{
  int i = blockIdx.x * blockDim.x + threadIdx.x;
  if (i < E) {
    int r = recv[i];
    int p = atomicAdd(&cursor[r], 1);
    csr[p] = make_int2(send[i], __float_as_int(ew[i]));
  }
}

// ---------- fused SpMM + gate accumulate (fp16 x, scale-tracked) ----------
// wave per receiver node, lane = channel. xin stored with true scale s_in;
// acc = sum_e w_e xin[s_e]  (stored units, fp32 accum);
// x_next = fp16(acc/16)  (scale s_in*16);
// out += sigmoid(s_in*acc.Wg + bg) * (s_in*acc).
__global__ __launch_bounds__(256) void spmm_gate(
    const ushort* __restrict__ x, const int* __restrict__ row_start,
    const int2* __restrict__ csr, const float* __restrict__ Wg,
    const float* __restrict__ bgp, ushort* __restrict__ x_next,
    float* __restrict__ out, int n, float s_in)
{
  int t = threadIdx.x;
  int lane = t & 63, wid = t >> 6;
  int wave = blockIdx.x * (blockDim.x >> 6) + wid;
  int nw = gridDim.x * (blockDim.x >> 6);
  float wg = Wg[lane], bgv = bgp[0];

  for (int node = wave; node < n; node += nw) {
    int beg = row_start[node], end = row_start[node + 1];
    float a0 = 0.f, a1 = 0.f, a2 = 0.f, a3 = 0.f;
    float a4 = 0.f, a5 = 0.f, a6 = 0.f, a7 = 0.f;
    for (int base = beg; base < end; base += 64) {
      int2 ev = make_int2(0, 0);
      if (base + lane < end) ev = csr[base + lane];
      int cnt = end - base; if (cnt > 64) cnt = 64;
      int j = 0;
      for (; j + 8 <= cnt; j += 8) {
        int   s0 = __shfl(ev.x, j + 0, 64), s1 = __shfl(ev.x, j + 1, 64);
        int   s2 = __shfl(ev.x, j + 2, 64), s3 = __shfl(ev.x, j + 3, 64);
        int   s4 = __shfl(ev.x, j + 4, 64), s5 = __shfl(ev.x, j + 5, 64);
        int   s6 = __shfl(ev.x, j + 6, 64), s7 = __shfl(ev.x, j + 7, 64);
        float w0 = __int_as_float(__shfl(ev.y, j + 0, 64));
        float w1 = __int_as_float(__shfl(ev.y, j + 1, 64));
        float w2 = __int_as_float(__shfl(ev.y, j + 2, 64));
        float w3 = __int_as_float(__shfl(ev.y, j + 3, 64));
        float w4 = __int_as_float(__shfl(ev.y, j + 4, 64));
        float w5 = __int_as_float(__shfl(ev.y, j + 5, 64));
        float w6 = __int_as_float(__shfl(ev.y, j + 6, 64));
        float w7 = __int_as_float(__shfl(ev.y, j + 7, 64));
        ushort u0 = x[(unsigned)(s0 * C) + lane];
        ushort u1 = x[(unsigned)(s1 * C) + lane];
        ushort u2 = x[(unsigned)(s2 * C) + lane];
        ushort u3 = x[(unsigned)(s3 * C) + lane];
        ushort u4 = x[(unsigned)(s4 * C) + lane];
        ushort u5 = x[(unsigned)(s5 * C) + lane];
        ushort u6 = x[(unsigned)(s6 * C) + lane];
        ushort u7 = x[(unsigned)(s7 * C) + lane];
        a0 += w0 * h2f(u0); a1 += w1 * h2f(u1);
        a2 += w2 * h2f(u2); a3 += w3 * h2f(u3);
        a4 += w4 * h2f(u4); a5 += w5 * h2f(u5);
        a6 += w6 * h2f(u6); a7 += w7 * h2f(u7);
      }
      for (; j < cnt; ++j) {
        int sj = __shfl(ev.x, j, 64);
        float wj = __int_as_float(__shfl(ev.y, j, 64));
        a0 += wj * h2f(x[(unsigned)(sj * C) + lane]);
      }
    }
    float acc = ((a0 + a1) + (a2 + a3)) + ((a4 + a5) + (a6 + a7));
    float p = acc * wg;
#pragma unroll
    for (int off = 32; off > 0; off >>= 1) p += __shfl_xor(p, off, 64);
    float g = 1.f / (1.f + expf(-(p * s_in + bgv)));
    size_t o = (size_t)node * C + lane;
    x_next[o] = f2h(acc * 0.0625f);
    out[o] += g * (acc * s_in);
  }
}

// ---------------------------------------------------------------------------
extern "C" void kernel_launch(void* const* d_in, const int* in_sizes, int n_in,
                              void* d_out, int out_size, void* d_ws, size_t ws_size,
                              hipStream_t stream) {
  const float* nf   = (const float*)d_in[0];
  const float* ew   = (const float*)d_in[1];
  const float* W1   = (const float*)d_in[2];
  const float* b1   = (const float*)d_in[3];
  const float* W2   = (const float*)d_in[4];
  const float* b2   = (const float*)d_in[5];
  const float* Wg   = (const float*)d_in[6];
  const float* bg   = (const float*)d_in[7];
  const int* send   = (const int*)d_in[8];
  const int* recv   = (const int*)d_in[9];
  float* out = (float*)d_out;

  int n = in_sizes[0] / F_IN;     // 100000
  int E = in_sizes[1];            // 3200000

  // workspace layout (4B units)
  float*  hbuf = (float*)d_ws;                      // n*64 fp32: h
  ushort* xA   = (ushort*)(hbuf + (size_t)n * C);   // n*64 fp16: x even
  ushort* xB   = xA + (size_t)n * C;                // n*64 fp16: x odd
  int2*   csr  = (int2*)(xB + (size_t)n * C);       // E packed (send, w)
  int* row_start = (int*)(csr + E);                 // n+1
  int* cursor    = row_start + (n + 1);             // n (histogram -> cursor)

  // 1) h = relu(nf@W1+b1)  -> hbuf
  gemm1_relu<<<(n + 63) / 64, 256, 0, stream>>>(nf, W1, b1, hbuf, n);

  // 2) logits = h@W2+b2 ; x0=fp16(logits) -> xA ; out = sig(logits.Wg+bg)*logits
  gemm2_gate<<<(n + 3) / 4, 256, 0, stream>>>(hbuf, W2, b2, Wg, bg, xA, out, n);

  // 3) CSR build (receiver-major, packed int2)
  zero_int<<<(n + 255) / 256, 256, 0, stream>>>(cursor, n);
  hist_recv<<<(E + 255) / 256, 256, 0, stream>>>(recv, cursor, E);
  scan_counts<<<1, 1024, 0, stream>>>(cursor, row_start, n);
  scatter_edges<<<(E + 255) / 256, 256, 0, stream>>>(send, recv, ew, cursor,
                                                     csr, E);

  // 4) 20 propagation hops, gate-fused. x ping-pongs xA <-> xB.
  //    stored x_k has true scale 16^k (exact fp32 powers of two).
  ushort* xin = xA;
  ushort* xout = xB;
  for (int k = 0; k < 20; ++k) {
    float s_in = ldexpf(1.0f, 4 * k);   // 16^k, exact
    spmm_gate<<<(n + 3) / 4, 256, 0, stream>>>(xin, row_start, csr, Wg, bg,
                                               xout, out, n, s_in);
    ushort* tmp = xin; xin = xout; xout = tmp;
  }
}

// Round 7
// 2257.588 us; speedup vs baseline: 2.2289x; 1.1070x over previous
//
#include <hip/hip_runtime.h>
#include <math.h>

// ---------------------------------------------------------------------------
// DAGNN: h=relu(nf@W1+b1); logits=h@W2+b2; 20x (x<-A x) with gated sum
// out = sum_k sigmoid(x_k . Wg + bg) * x_k    (k=0..20, x_0 = logits)
//
// Round-6 (resubmit; round-6 bench was an infra timeout):
//  - paired-edge gather: 2 edges per wave-load (ushort2/lane, per-lane shfl
//    index j+(lane>>5)) -> half the gather instrs + half the broadcasts.
//  - deferred gate: hops write x_k into slot k of [21][n][64] fp16; one
//    final gate_sum pass computes out (kills 20x out-RMW, ~200 us).
//    Runtime ws_size check; falls back to round-5 fused-gate path if the
//    slot array doesn't fit.
//  - x fp16 with per-hop 1/16 rescale (scale 16^k, exact fp32) as round-5.
// ---------------------------------------------------------------------------

#define F_IN 512
#define C 64  // hidden == n_classes == 64

__device__ inline float h2f(ushort u) {
  _Float16 h; __builtin_memcpy(&h, &u, 2); return (float)h;
}
__device__ inline ushort f2h(float f) {
  _Float16 h = (_Float16)f; ushort u; __builtin_memcpy(&u, &h, 2); return u;
}

// ---------- GEMM1: [M,512] @ [512,64] + b1, relu --------------------------
__global__ __launch_bounds__(256) void gemm1_relu(
    const float* __restrict__ A, const float* __restrict__ W1,
    const float* __restrict__ b1, float* __restrict__ H, int M)
{
  __shared__ __align__(16) float As[16][68];  // transposed [k][m], pad to 68
  __shared__ __align__(16) float Bs[16][64];
  int t = threadIdx.x;
  int tx = t & 15, ty = t >> 4;
  int m0 = blockIdx.x * 64;
  int lm = t >> 2, lk = (t & 3) << 2;
  const float* Arow = A + (size_t)(m0 + lm) * F_IN;
  bool aok = (m0 + lm) < M;
  float acc[4][4] = {};

  for (int k0 = 0; k0 < F_IN; k0 += 16) {
    float4 av = make_float4(0.f, 0.f, 0.f, 0.f);
    if (aok) av = *(const float4*)(Arow + k0 + lk);
    float bv[4];
#pragma unroll
    for (int i = 0; i < 4; ++i)
      bv[i] = W1[(size_t)(k0 + (t >> 6) + (i << 2)) * C + (t & 63)];
    __syncthreads();
    As[lk + 0][lm] = av.x; As[lk + 1][lm] = av.y;
    As[lk + 2][lm] = av.z; As[lk + 3][lm] = av.w;
#pragma unroll
    for (int i = 0; i < 4; ++i)
      Bs[(t >> 6) + (i << 2)][t & 63] = bv[i];
    __syncthreads();
#pragma unroll
    for (int kk = 0; kk < 16; ++kk) {
      float4 a = *(const float4*)&As[kk][ty << 2];
      float4 b = *(const float4*)&Bs[kk][tx << 2];
      acc[0][0] += a.x * b.x; acc[0][1] += a.x * b.y; acc[0][2] += a.x * b.z; acc[0][3] += a.x * b.w;
      acc[1][0] += a.y * b.x; acc[1][1] += a.y * b.y; acc[1][2] += a.y * b.z; acc[1][3] += a.y * b.w;
      acc[2][0] += a.z * b.x; acc[2][1] += a.z * b.y; acc[2][2] += a.z * b.z; acc[2][3] += a.z * b.w;
      acc[3][0] += a.w * b.x; acc[3][1] += a.w * b.y; acc[3][2] += a.w * b.z; acc[3][3] += a.w * b.w;
    }
    __syncthreads();
  }
  float4 bb = *(const float4*)&b1[tx << 2];
#pragma unroll
  for (int i = 0; i < 4; ++i) {
    int row = m0 + (ty << 2) + i;
    if (row < M) {
      float4 r;
      r.x = fmaxf(acc[i][0] + bb.x, 0.f);
      r.y = fmaxf(acc[i][1] + bb.y, 0.f);
      r.z = fmaxf(acc[i][2] + bb.z, 0.f);
      r.w = fmaxf(acc[i][3] + bb.w, 0.f);
      *(float4*)&H[(size_t)row * C + (tx << 2)] = r;
    }
  }
}

// ---------- GEMM2: logits = h@W2+b2 (fp32); x0 = fp16(logits).
// write_out!=0: also out = sig(logits.Wg+bg)*logits (fallback path).
__global__ __launch_bounds__(256) void gemm2_gate(
    const float* __restrict__ h, const float* __restrict__ W2,
    const float* __restrict__ b2, const float* __restrict__ Wg,
    const float* __restrict__ bgp, ushort* __restrict__ x0,
    float* __restrict__ out, int n, int write_out)
{
  __shared__ float W2s[C * C];
  int t = threadIdx.x;
  for (int i = t; i < C * C; i += blockDim.x) W2s[i] = W2[i];
  __syncthreads();
  int lane = t & 63, wid = t >> 6;
  int wave = blockIdx.x * (blockDim.x >> 6) + wid;
  int nw = gridDim.x * (blockDim.x >> 6);
  float wg = Wg[lane], bgv = bgp[0], b2v = b2[lane];
  for (int node = wave; node < n; node += nw) {
    float hv = h[(size_t)node * C + lane];
    float acc = b2v;
#pragma unroll
    for (int k = 0; k < C; ++k) {
      float hk = __shfl(hv, k, 64);
      acc += hk * W2s[k * C + lane];
    }
    size_t o = (size_t)node * C + lane;
    x0[o] = f2h(acc);
    if (write_out) {
      float p = acc * wg;
#pragma unroll
      for (int off = 32; off > 0; off >>= 1) p += __shfl_xor(p, off, 64);
      float g = 1.f / (1.f + expf(-(p + bgv)));
      out[o] = g * acc;
    }
  }
}

// ---------- CSR build (receiver-major) ------------------------------------
__global__ void zero_int(int* __restrict__ p, int n) {
  int i = blockIdx.x * blockDim.x + threadIdx.x;
  if (i < n) p[i] = 0;
}

__global__ void hist_recv(const int* __restrict__ recv, int* __restrict__ cnt, int E) {
  int i = blockIdx.x * blockDim.x + threadIdx.x;
  if (i < E) atomicAdd(&cnt[recv[i]], 1);
}

// single-block exclusive scan; writes row_start[0..n] and cursor (aliases cnt)
__global__ __launch_bounds__(1024) void scan_counts(
    int* __restrict__ cnt_cursor, int* __restrict__ row_start, int n)
{
  __shared__ int wsum[16];
  int t = threadIdx.x, lane = t & 63, wid = t >> 6;
  int carry = 0;
  for (int base = 0; base < n; base += 1024) {
    int idx = base + t;
    int v = (idx < n) ? cnt_cursor[idx] : 0;
    int incl = v;
#pragma unroll
    for (int off = 1; off < 64; off <<= 1) {
      int u = __shfl_up(incl, off, 64);
      if (lane >= off) incl += u;
    }
    if (lane == 63) wsum[wid] = incl;
    __syncthreads();
    if (t < 16) {
      int ws = wsum[t];
#pragma unroll
      for (int off = 1; off < 16; off <<= 1) {
        int u = __shfl_up(ws, off, 16);
        if ((t & 15) >= off) ws += u;
      }
      wsum[t] = ws;
    }
    __syncthreads();
    int woff = (wid > 0) ? wsum[wid - 1] : 0;
    int total = wsum[15];
    int excl = carry + woff + (incl - v);
    if (idx < n) { row_start[idx] = excl; cnt_cursor[idx] = excl; }
    carry += total;
    __syncthreads();
  }
  if (t == 0) row_start[n] = carry;
}

// scatter: packed (sender, weight_bits) -> ONE 8B store per edge.
__global__ void scatter_edges(
    const int* __restrict__ send, const int* __restrict__ recv,
    const float* __restrict__ ew, int* __restrict__ cursor,
    int2* __restrict__ csr, int E)
{
  int i = blockIdx.x * blockDim.x + threadIdx.x;
  if (i < E) {
    int r = recv[i];
    int p = atomicAdd(&cursor[r], 1);
    csr[p] = make_int2(send[i], __float_as_int(ew[i]));
  }
}

// ---------- paired-edge SpMM (no gate): x_next = fp16((A x)/16) -----------
// Lanes 0-31 take edge j, lanes 32-63 edge j+1; each lane loads ushort2
// (channels 2(l&31), 2(l&31)+1). Per-lane shfl index j+(lane>>5) broadcasts
// each half its own edge. Padded staging entries are (0,0) -> w=0, harmless.
__global__ __launch_bounds__(256) void spmm_pair(
    const ushort* __restrict__ x, const int* __restrict__ row_start,
    const int2* __restrict__ csr, ushort* __restrict__ x_next, int n)
{
  int t = threadIdx.x;
  int lane = t & 63, wid = t >> 6;
  int half = lane >> 5;
  int ch2 = (lane & 31) << 1;
  int wave = blockIdx.x * 4 + wid;
  int nw = gridDim.x * 4;

  for (int node = wave; node < n; node += nw) {
    int beg = row_start[node], end = row_start[node + 1];
    float ax0 = 0.f, ay0 = 0.f, ax1 = 0.f, ay1 = 0.f;
    float ax2 = 0.f, ay2 = 0.f, ax3 = 0.f, ay3 = 0.f;
    for (int base = beg; base < end; base += 64) {
      int2 ev = make_int2(0, 0);
      if (base + lane < end) ev = csr[base + lane];
      int cnt = end - base; if (cnt > 64) cnt = 64;
      int j = 0;
      for (; j + 8 <= cnt; j += 8) {     // 4 pairs = 8 edges
        int i0 = j + 0 + half, i1 = j + 2 + half;
        int i2 = j + 4 + half, i3 = j + 6 + half;
        int   s0 = __shfl(ev.x, i0, 64), s1 = __shfl(ev.x, i1, 64);
        int   s2 = __shfl(ev.x, i2, 64), s3 = __shfl(ev.x, i3, 64);
        float w0 = __int_as_float(__shfl(ev.y, i0, 64));
        float w1 = __int_as_float(__shfl(ev.y, i1, 64));
        float w2 = __int_as_float(__shfl(ev.y, i2, 64));
        float w3 = __int_as_float(__shfl(ev.y, i3, 64));
        ushort2 u0 = *(const ushort2*)&x[(unsigned)(s0 * C) + ch2];
        ushort2 u1 = *(const ushort2*)&x[(unsigned)(s1 * C) + ch2];
        ushort2 u2 = *(const ushort2*)&x[(unsigned)(s2 * C) + ch2];
        ushort2 u3 = *(const ushort2*)&x[(unsigned)(s3 * C) + ch2];
        ax0 += w0 * h2f(u0.x); ay0 += w0 * h2f(u0.y);
        ax1 += w1 * h2f(u1.x); ay1 += w1 * h2f(u1.y);
        ax2 += w2 * h2f(u2.x); ay2 += w2 * h2f(u2.y);
        ax3 += w3 * h2f(u3.x); ay3 += w3 * h2f(u3.y);
      }
      for (; j < cnt; j += 2) {          // tail pairs (odd tail: w=0 pad)
        int i0 = j + half;
        int s0 = __shfl(ev.x, i0, 64);
        float w0 = __int_as_float(__shfl(ev.y, i0, 64));
        ushort2 u0 = *(const ushort2*)&x[(unsigned)(s0 * C) + ch2];
        ax0 += w0 * h2f(u0.x); ay0 += w0 * h2f(u0.y);
      }
    }
    float sx = (ax0 + ax1) + (ax2 + ax3);
    float sy = (ay0 + ay1) + (ay2 + ay3);
    sx += __shfl_xor(sx, 32, 64);        // combine the two halves
    sy += __shfl_xor(sy, 32, 64);
    if (half == 0) {
      ushort2 uv;
      uv.x = f2h(sx * 0.0625f);
      uv.y = f2h(sy * 0.0625f);
      *(ushort2*)&x_next[(size_t)node * C + ch2] = uv;
    }
  }
}

// ---------- final deferred gate pass --------------------------------------
// out[node] = sum_k sigmoid((x_k.Wg)*16^k + bg) * x_k * 16^k, x_k from slots.
__global__ __launch_bounds__(256) void gate_sum(
    const ushort* __restrict__ slots, const float* __restrict__ Wg,
    const float* __restrict__ bgp, float* __restrict__ out,
    int n, int K1, size_t slotStride)
{
  int t = threadIdx.x;
  int lane = t & 63, wid = t >> 6;
  int wave = blockIdx.x * 4 + wid;
  int nw = gridDim.x * 4;
  float wg = Wg[lane], bgv = bgp[0];
  for (int node = wave; node < n; node += nw) {
    float acc = 0.f;
    float scale = 1.f;
    size_t o = (size_t)node * C + lane;
    for (int k = 0; k < K1; ++k) {
      float v = h2f(slots[(size_t)k * slotStride + o]);
      float p = v * wg;
#pragma unroll
      for (int off = 32; off > 0; off >>= 1) p += __shfl_xor(p, off, 64);
      float g = 1.f / (1.f + expf(-(p * scale + bgv)));
      acc += g * (v * scale);
      scale *= 16.f;
    }
    out[o] = acc;
  }
}

// ---------- fallback: round-5 fused SpMM+gate (fp16, scale-tracked) -------
__global__ __launch_bounds__(256) void spmm_gate(
    const ushort* __restrict__ x, const int* __restrict__ row_start,
    const int2* __restrict__ csr, const float* __restrict__ Wg,
    const float* __restrict__ bgp, ushort* __restrict__ x_next,
    float* __restrict__ out, int n, float s_in)
{
  int t = threadIdx.x;
  int lane = t & 63, wid = t >> 6;
  int wave = blockIdx.x * (blockDim.x >> 6) + wid;
  int nw = gridDim.x * (blockDim.x >> 6);
  float wg = Wg[lane], bgv = bgp[0];

  for (int node = wave; node < n; node += nw) {
    int beg = row_start[node], end = row_start[node + 1];
    float a0 = 0.f, a1 = 0.f, a2 = 0.f, a3 = 0.f;
    for (int base = beg; base < end; base += 64) {
      int2 ev = make_int2(0, 0);
      if (base + lane < end) ev = csr[base + lane];
      int cnt = end - base; if (cnt > 64) cnt = 64;
      int j = 0;
      for (; j + 4 <= cnt; j += 4) {
        int   s0 = __shfl(ev.x, j + 0, 64), s1 = __shfl(ev.x, j + 1, 64);
        int   s2 = __shfl(ev.x, j + 2, 64), s3 = __shfl(ev.x, j + 3, 64);
        float w0 = __int_as_float(__shfl(ev.y, j + 0, 64));
        float w1 = __int_as_float(__shfl(ev.y, j + 1, 64));
        float w2 = __int_as_float(__shfl(ev.y, j + 2, 64));
        float w3 = __int_as_float(__shfl(ev.y, j + 3, 64));
        a0 += w0 * h2f(x[(unsigned)(s0 * C) + lane]);
        a1 += w1 * h2f(x[(unsigned)(s1 * C) + lane]);
        a2 += w2 * h2f(x[(unsigned)(s2 * C) + lane]);
        a3 += w3 * h2f(x[(unsigned)(s3 * C) + lane]);
      }
      for (; j < cnt; ++j) {
        int sj = __shfl(ev.x, j, 64);
        float wj = __int_as_float(__shfl(ev.y, j, 64));
        a0 += wj * h2f(x[(unsigned)(sj * C) + lane]);
      }
    }
    float acc = (a0 + a1) + (a2 + a3);
    float p = acc * wg;
#pragma unroll
    for (int off = 32; off > 0; off >>= 1) p += __shfl_xor(p, off, 64);
    float g = 1.f / (1.f + expf(-(p * s_in + bgv)));
    size_t o = (size_t)node * C + lane;
    x_next[o] = f2h(acc * 0.0625f);
    out[o] += g * (acc * s_in);
  }
}

// ---------------------------------------------------------------------------
extern "C" void kernel_launch(void* const* d_in, const int* in_sizes, int n_in,
                              void* d_out, int out_size, void* d_ws, size_t ws_size,
                              hipStream_t stream) {
  const float* nf   = (const float*)d_in[0];
  const float* ew   = (const float*)d_in[1];
  const float* W1   = (const float*)d_in[2];
  const float* b1   = (const float*)d_in[3];
  const float* W2   = (const float*)d_in[4];
  const float* b2   = (const float*)d_in[5];
  const float* Wg   = (const float*)d_in[6];
  const float* bg   = (const float*)d_in[7];
  const int* send   = (const int*)d_in[8];
  const int* recv   = (const int*)d_in[9];
  float* out = (float*)d_out;

  int n = in_sizes[0] / F_IN;     // 100000
  int E = in_sizes[1];            // 3200000
  const int K = 20;

  size_t slotElems = (size_t)n * C;          // ushorts per slot
  // deferred layout: hbuf fp32 | slots[(K+1)] fp16 | csr int2 | row_start | cursor
  size_t need = slotElems * 4                      // hbuf
              + (size_t)(K + 1) * slotElems * 2    // slots
              + (size_t)E * 8                      // csr
              + (size_t)(2 * n + 1) * 4;           // row_start + cursor

  if (ws_size >= need) {
    // ---------------- deferred-gate path ----------------
    float*  hbuf = (float*)d_ws;
    ushort* slots = (ushort*)(hbuf + slotElems);
    int2*   csr  = (int2*)(slots + (size_t)(K + 1) * slotElems);
    int* row_start = (int*)(csr + E);
    int* cursor    = row_start + (n + 1);

    gemm1_relu<<<(n + 63) / 64, 256, 0, stream>>>(nf, W1, b1, hbuf, n);
    gemm2_gate<<<(n + 3) / 4, 256, 0, stream>>>(hbuf, W2, b2, Wg, bg,
                                                slots, out, n, /*write_out=*/0);

    zero_int<<<(n + 255) / 256, 256, 0, stream>>>(cursor, n);
    hist_recv<<<(E + 255) / 256, 256, 0, stream>>>(recv, cursor, E);
    scan_counts<<<1, 1024, 0, stream>>>(cursor, row_start, n);
    scatter_edges<<<(E + 255) / 256, 256, 0, stream>>>(send, recv, ew, cursor,
                                                       csr, E);

    for (int k = 0; k < K; ++k) {
      spmm_pair<<<(n + 3) / 4, 256, 0, stream>>>(
          slots + (size_t)k * slotElems, row_start, csr,
          slots + (size_t)(k + 1) * slotElems, n);
    }
    gate_sum<<<(n + 3) / 4, 256, 0, stream>>>(slots, Wg, bg, out, n, K + 1,
                                              slotElems);
  } else {
    // ---------------- fallback: round-5 fused path ----------------
    float*  hbuf = (float*)d_ws;
    ushort* xA   = (ushort*)(hbuf + slotElems);
    ushort* xB   = xA + slotElems;
    int2*   csr  = (int2*)(xB + slotElems);
    int* row_start = (int*)(csr + E);
    int* cursor    = row_start + (n + 1);

    gemm1_relu<<<(n + 63) / 64, 256, 0, stream>>>(nf, W1, b1, hbuf, n);
    gemm2_gate<<<(n + 3) / 4, 256, 0, stream>>>(hbuf, W2, b2, Wg, bg,
                                                xA, out, n, /*write_out=*/1);

    zero_int<<<(n + 255) / 256, 256, 0, stream>>>(cursor, n);
    hist_recv<<<(E + 255) / 256, 256, 0, stream>>>(recv, cursor, E);
    scan_counts<<<1, 1024, 0, stream>>>(cursor, row_start, n);
    scatter_edges<<<(E + 255) / 256, 256, 0, stream>>>(send, recv, ew, cursor,
                                                       csr, E);

    ushort* xin = xA;
    ushort* xout = xB;
    for (int k = 0; k < K; ++k) {
      float s_in = ldexpf(1.0f, 4 * k);   // 16^k, exact
      spmm_gate<<<(n + 3) / 4, 256, 0, stream>>>(xin, row_start, csr, Wg, bg,
                                                 xout, out, n, s_in);
      ushort* tmp = xin; xin = xout; xout = tmp;
    }
  }
}

// Round 10
// 2049.538 us; speedup vs baseline: 2.4551x; 1.1015x over previous
//
#include <hip/hip_runtime.h>
#include <math.h>

// ---------------------------------------------------------------------------
// DAGNN: h=relu(nf@W1+b1); logits=h@W2+b2; 20x (x<-A x) with gated sum
// out = sum_k sigmoid(x_k . Wg + bg) * x_k    (k=0..20, x_0 = logits)
//
// Round-8 (3rd submit; infra timeouts): two-phase binned CSR build
// replaces the random scatter (198MB dirty-line writes -> ~65MB):
//   A) bin_edges: LDS-reorder 4096-edge chunks by bucket=recv>>9 (196
//      buckets), flush contiguous runs into ibuf at row_start[b<<9] offsets.
//   B) scatter_bucket: one block per bucket, LDS per-receiver cursors,
//      writes confined to a 131KB L2-resident window -> dirty lines merge.
// ibuf aliases slots[1..2] (unused until hop 1) -> no extra workspace.
// SpMM (fp16 paired-edge, deferred gate) unchanged from round 7.
// ---------------------------------------------------------------------------

#define F_IN 512
#define C 64        // hidden == n_classes == 64
#define BSHIFT 9    // bucket = recv >> 9  (512 receivers/bucket)
#define BMASK ((1 << BSHIFT) - 1)
#define CHUNK 4096  // edges per bin_edges block
#define EPT 16      // edges per thread in bin_edges

__device__ inline float h2f(ushort u) {
  _Float16 h; __builtin_memcpy(&h, &u, 2); return (float)h;
}
__device__ inline ushort f2h(float f) {
  _Float16 h = (_Float16)f; ushort u; __builtin_memcpy(&u, &h, 2); return u;
}

// ---------- GEMM1: [M,512] @ [512,64] + b1, relu --------------------------
__global__ __launch_bounds__(256) void gemm1_relu(
    const float* __restrict__ A, const float* __restrict__ W1,
    const float* __restrict__ b1, float* __restrict__ H, int M)
{
  __shared__ __align__(16) float As[16][68];  // transposed [k][m], pad to 68
  __shared__ __align__(16) float Bs[16][64];
  int t = threadIdx.x;
  int tx = t & 15, ty = t >> 4;
  int m0 = blockIdx.x * 64;
  int lm = t >> 2, lk = (t & 3) << 2;
  const float* Arow = A + (size_t)(m0 + lm) * F_IN;
  bool aok = (m0 + lm) < M;
  float acc[4][4] = {};

  for (int k0 = 0; k0 < F_IN; k0 += 16) {
    float4 av = make_float4(0.f, 0.f, 0.f, 0.f);
    if (aok) av = *(const float4*)(Arow + k0 + lk);
    float bv[4];
#pragma unroll
    for (int i = 0; i < 4; ++i)
      bv[i] = W1[(size_t)(k0 + (t >> 6) + (i << 2)) * C + (t & 63)];
    __syncthreads();
    As[lk + 0][lm] = av.x; As[lk + 1][lm] = av.y;
    As[lk + 2][lm] = av.z; As[lk + 3][lm] = av.w;
#pragma unroll
    for (int i = 0; i < 4; ++i)
      Bs[(t >> 6) + (i << 2)][t & 63] = bv[i];
    __syncthreads();
#pragma unroll
    for (int kk = 0; kk < 16; ++kk) {
      float4 a = *(const float4*)&As[kk][ty << 2];
      float4 b = *(const float4*)&Bs[kk][tx << 2];
      acc[0][0] += a.x * b.x; acc[0][1] += a.x * b.y; acc[0][2] += a.x * b.z; acc[0][3] += a.x * b.w;
      acc[1][0] += a.y * b.x; acc[1][1] += a.y * b.y; acc[1][2] += a.y * b.z; acc[1][3] += a.y * b.w;
      acc[2][0] += a.z * b.x; acc[2][1] += a.z * b.y; acc[2][2] += a.z * b.z; acc[2][3] += a.z * b.w;
      acc[3][0] += a.w * b.x; acc[3][1] += a.w * b.y; acc[3][2] += a.w * b.z; acc[3][3] += a.w * b.w;
    }
    __syncthreads();
  }
  float4 bb = *(const float4*)&b1[tx << 2];
#pragma unroll
  for (int i = 0; i < 4; ++i) {
    int row = m0 + (ty << 2) + i;
    if (row < M) {
      float4 r;
      r.x = fmaxf(acc[i][0] + bb.x, 0.f);
      r.y = fmaxf(acc[i][1] + bb.y, 0.f);
      r.z = fmaxf(acc[i][2] + bb.z, 0.f);
      r.w = fmaxf(acc[i][3] + bb.w, 0.f);
      *(float4*)&H[(size_t)row * C + (tx << 2)] = r;
    }
  }
}

// ---------- GEMM2: logits = h@W2+b2 (fp32); x0 = fp16(logits).
// write_out!=0: also out = sig(logits.Wg+bg)*logits (fallback path).
__global__ __launch_bounds__(256) void gemm2_gate(
    const float* __restrict__ h, const float* __restrict__ W2,
    const float* __restrict__ b2, const float* __restrict__ Wg,
    const float* __restrict__ bgp, ushort* __restrict__ x0,
    float* __restrict__ out, int n, int write_out)
{
  __shared__ float W2s[C * C];
  int t = threadIdx.x;
  for (int i = t; i < C * C; i += blockDim.x) W2s[i] = W2[i];
  __syncthreads();
  int lane = t & 63, wid = t >> 6;
  int wave = blockIdx.x * (blockDim.x >> 6) + wid;
  int nw = gridDim.x * (blockDim.x >> 6);
  float wg = Wg[lane], bgv = bgp[0], b2v = b2[lane];
  for (int node = wave; node < n; node += nw) {
    float hv = h[(size_t)node * C + lane];
    float acc = b2v;
#pragma unroll
    for (int k = 0; k < C; ++k) {
      float hk = __shfl(hv, k, 64);
      acc += hk * W2s[k * C + lane];
    }
    size_t o = (size_t)node * C + lane;
    x0[o] = f2h(acc);
    if (write_out) {
      float p = acc * wg;
#pragma unroll
      for (int off = 32; off > 0; off >>= 1) p += __shfl_xor(p, off, 64);
      float g = 1.f / (1.f + expf(-(p + bgv)));
      out[o] = g * acc;
    }
  }
}

// ---------- CSR build (receiver-major) ------------------------------------
__global__ void zero_int(int* __restrict__ p, int n) {
  int i = blockIdx.x * blockDim.x + threadIdx.x;
  if (i < n) p[i] = 0;
}

__global__ void hist_recv(const int* __restrict__ recv, int* __restrict__ cnt, int E) {
  int i = blockIdx.x * blockDim.x + threadIdx.x;
  if (i < E) atomicAdd(&cnt[recv[i]], 1);
}

// single-block exclusive scan; writes row_start[0..n] and cursor (aliases cnt)
__global__ __launch_bounds__(1024) void scan_counts(
    int* __restrict__ cnt_cursor, int* __restrict__ row_start, int n)
{
  __shared__ int wsum[16];
  int t = threadIdx.x, lane = t & 63, wid = t >> 6;
  int carry = 0;
  for (int base = 0; base < n; base += 1024) {
    int idx = base + t;
    int v = (idx < n) ? cnt_cursor[idx] : 0;
    int incl = v;
#pragma unroll
    for (int off = 1; off < 64; off <<= 1) {
      int u = __shfl_up(incl, off, 64);
      if (lane >= off) incl += u;
    }
    if (lane == 63) wsum[wid] = incl;
    __syncthreads();
    if (t < 16) {
      int ws = wsum[t];
#pragma unroll
      for (int off = 1; off < 16; off <<= 1) {
        int u = __shfl_up(ws, off, 16);
        if ((t & 15) >= off) ws += u;
      }
      wsum[t] = ws;
    }
    __syncthreads();
    int woff = (wid > 0) ? wsum[wid - 1] : 0;
    int total = wsum[15];
    int excl = carry + woff + (incl - v);
    if (idx < n) { row_start[idx] = excl; cnt_cursor[idx] = excl; }
    carry += total;
    __syncthreads();
  }
  if (t == 0) row_start[n] = carry;
}

__global__ void init_gcur(const int* __restrict__ row_start,
                          int* __restrict__ gcur, int NB) {
  int t = blockIdx.x * blockDim.x + threadIdx.x;
  if (t < NB) gcur[t] = row_start[t << BSHIFT];
}

// ---- phase A: LDS-reorder chunk by bucket, flush contiguous runs ---------
// packed intermediate: .x = send | (recvlow9 << 17)  (send < 2^17), .y = w
__global__ __launch_bounds__(256) void bin_edges(
    const int* __restrict__ send, const int* __restrict__ recv,
    const float* __restrict__ ew, int* __restrict__ gcur,
    int2* __restrict__ ibuf, int E, int NB)
{
  __shared__ int cnt[256];     // histogram -> LDS cursor
  __shared__ int offs[256];    // exclusive offsets (stable copy)
  __shared__ int gb[256];      // global base per bucket (this chunk)
  __shared__ int wsum[4];
  __shared__ int2 stage[CHUNK];
  __shared__ unsigned char sb[CHUNK];

  int t = threadIdx.x;
  int base = blockIdx.x * CHUNK;
  int valid = E - base; if (valid > CHUNK) valid = CHUNK;

  cnt[t] = 0;
  __syncthreads();

  int2 pk[EPT];
  int bk[EPT];
#pragma unroll
  for (int r = 0; r < EPT; ++r) {
    int e = base + r * 256 + t;
    bk[r] = -1;
    if (e < E) {
      int rc = recv[e];
      int b = rc >> BSHIFT;
      pk[r] = make_int2(send[e] | ((rc & BMASK) << 17), __float_as_int(ew[e]));
      bk[r] = b;
      atomicAdd(&cnt[b], 1);
    }
  }
  __syncthreads();

  // 256-wide exclusive scan of cnt; reserve global space per bucket
  {
    int lane = t & 63, wid = t >> 6;
    int v = cnt[t];
    int incl = v;
#pragma unroll
    for (int off = 1; off < 64; off <<= 1) {
      int u = __shfl_up(incl, off, 64);
      if (lane >= off) incl += u;
    }
    if (lane == 63) wsum[wid] = incl;
    __syncthreads();
    int w0 = wsum[0], w1 = wsum[1], w2 = wsum[2];
    int woff = (wid == 0) ? 0 : (wid == 1) ? w0 : (wid == 2) ? w0 + w1
                                                             : w0 + w1 + w2;
    int excl = woff + incl - v;
    offs[t] = excl;
    if (t < NB && v > 0) gb[t] = atomicAdd(&gcur[t], v);
    cnt[t] = excl;   // becomes LDS cursor
  }
  __syncthreads();

  // stage bucket-ordered in LDS
#pragma unroll
  for (int r = 0; r < EPT; ++r) {
    if (bk[r] >= 0) {
      int slot = atomicAdd(&cnt[bk[r]], 1);
      stage[slot] = pk[r];
      sb[slot] = (unsigned char)bk[r];
    }
  }
  __syncthreads();

  // flush: contiguous per-bucket runs -> coalesced-ish global writes
  for (int s = t; s < valid; s += 256) {
    int b = sb[s];
    ibuf[gb[b] + (s - offs[b])] = stage[s];
  }
}

// ---- phase B: per-bucket fine scatter through LDS cursors ----------------
// Writes confined to a ~131KB csr window (one XCD L2) -> dirty lines merge.
__global__ __launch_bounds__(256) void scatter_bucket(
    const int2* __restrict__ ibuf, const int* __restrict__ row_start,
    int2* __restrict__ csr, int n)
{
  __shared__ int cur[1 << BSHIFT];
  int b = blockIdx.x;
  int nodeBase = b << BSHIFT;
  int nNodes = n - nodeBase; if (nNodes > (1 << BSHIFT)) nNodes = 1 << BSHIFT;
  int t = threadIdx.x;
  for (int i = t; i < nNodes; i += 256) cur[i] = row_start[nodeBase + i];
  __syncthreads();
  int beg = row_start[nodeBase];
  int end = row_start[nodeBase + nNodes];
  for (int i = beg + t; i < end; i += 256) {
    int2 e = ibuf[i];
    int rl = (e.x >> 17) & BMASK;
    int p = atomicAdd(&cur[rl], 1);
    csr[p] = make_int2(e.x & 0x1FFFF, e.y);
  }
}

// fallback-path scatter (random, packed 8B)
__global__ void scatter_edges(
    const int* __restrict__ send, const int* __restrict__ recv,
    const float* __restrict__ ew, int* __restrict__ cursor,
    int2* __restrict__ csr, int E)
{
  int i = blockIdx.x * blockDim.x + threadIdx.x;
  if (i < E) {
    int r = recv[i];
    int p = atomicAdd(&cursor[r], 1);
    csr[p] = make_int2(send[i], __float_as_int(ew[i]));
  }
}

// ---------- paired-edge SpMM (no gate): x_next = fp16((A x)/16) -----------
__global__ __launch_bounds__(256) void spmm_pair(
    const ushort* __restrict__ x, const int* __restrict__ row_start,
    const int2* __restrict__ csr, ushort* __restrict__ x_next, int n)
{
  int t = threadIdx.x;
  int lane = t & 63, wid = t >> 6;
  int half = lane >> 5;
  int ch2 = (lane & 31) << 1;
  int wave = blockIdx.x * 4 + wid;
  int nw = gridDim.x * 4;

  for (int node = wave; node < n; node += nw) {
    int beg = row_start[node], end = row_start[node + 1];
    float ax0 = 0.f, ay0 = 0.f, ax1 = 0.f, ay1 = 0.f;
    float ax2 = 0.f, ay2 = 0.f, ax3 = 0.f, ay3 = 0.f;
    for (int base = beg; base < end; base += 64) {
      int2 ev = make_int2(0, 0);
      if (base + lane < end) ev = csr[base + lane];
      int cnt = end - base; if (cnt > 64) cnt = 64;
      int j = 0;
      for (; j + 8 <= cnt; j += 8) {     // 4 pairs = 8 edges
        int i0 = j + 0 + half, i1 = j + 2 + half;
        int i2 = j + 4 + half, i3 = j + 6 + half;
        int   s0 = __shfl(ev.x, i0, 64), s1 = __shfl(ev.x, i1, 64);
        int   s2 = __shfl(ev.x, i2, 64), s3 = __shfl(ev.x, i3, 64);
        float w0 = __int_as_float(__shfl(ev.y, i0, 64));
        float w1 = __int_as_float(__shfl(ev.y, i1, 64));
        float w2 = __int_as_float(__shfl(ev.y, i2, 64));
        float w3 = __int_as_float(__shfl(ev.y, i3, 64));
        ushort2 u0 = *(const ushort2*)&x[(unsigned)(s0 * C) + ch2];
        ushort2 u1 = *(const ushort2*)&x[(unsigned)(s1 * C) + ch2];
        ushort2 u2 = *(const ushort2*)&x[(unsigned)(s2 * C) + ch2];
        ushort2 u3 = *(const ushort2*)&x[(unsigned)(s3 * C) + ch2];
        ax0 += w0 * h2f(u0.x); ay0 += w0 * h2f(u0.y);
        ax1 += w1 * h2f(u1.x); ay1 += w1 * h2f(u1.y);
        ax2 += w2 * h2f(u2.x); ay2 += w2 * h2f(u2.y);
        ax3 += w3 * h2f(u3.x); ay3 += w3 * h2f(u3.y);
      }
      for (; j < cnt; j += 2) {          // tail pairs (odd tail: w=0 pad)
        int i0 = j + half;
        int s0 = __shfl(ev.x, i0, 64);
        float w0 = __int_as_float(__shfl(ev.y, i0, 64));
        ushort2 u0 = *(const ushort2*)&x[(unsigned)(s0 * C) + ch2];
        ax0 += w0 * h2f(u0.x); ay0 += w0 * h2f(u0.y);
      }
    }
    float sx = (ax0 + ax1) + (ax2 + ax3);
    float sy = (ay0 + ay1) + (ay2 + ay3);
    sx += __shfl_xor(sx, 32, 64);
    sy += __shfl_xor(sy, 32, 64);
    if (half == 0) {
      ushort2 uv;
      uv.x = f2h(sx * 0.0625f);
      uv.y = f2h(sy * 0.0625f);
      *(ushort2*)&x_next[(size_t)node * C + ch2] = uv;
    }
  }
}

// ---------- final deferred gate pass --------------------------------------
__global__ __launch_bounds__(256) void gate_sum(
    const ushort* __restrict__ slots, const float* __restrict__ Wg,
    const float* __restrict__ bgp, float* __restrict__ out,
    int n, int K1, size_t slotStride)
{
  int t = threadIdx.x;
  int lane = t & 63, wid = t >> 6;
  int wave = blockIdx.x * 4 + wid;
  int nw = gridDim.x * 4;
  float wg = Wg[lane], bgv = bgp[0];
  for (int node = wave; node < n; node += nw) {
    float acc = 0.f;
    float scale = 1.f;
    size_t o = (size_t)node * C + lane;
    for (int k = 0; k < K1; ++k) {
      float v = h2f(slots[(size_t)k * slotStride + o]);
      float p = v * wg;
#pragma unroll
      for (int off = 32; off > 0; off >>= 1) p += __shfl_xor(p, off, 64);
      float g = 1.f / (1.f + expf(-(p * scale + bgv)));
      acc += g * (v * scale);
      scale *= 16.f;
    }
    out[o] = acc;
  }
}

// ---------- fallback: round-5 fused SpMM+gate (fp16, scale-tracked) -------
__global__ __launch_bounds__(256) void spmm_gate(
    const ushort* __restrict__ x, const int* __restrict__ row_start,
    const int2* __restrict__ csr, const float* __restrict__ Wg,
    const float* __restrict__ bgp, ushort* __restrict__ x_next,
    float* __restrict__ out, int n, float s_in)
{
  int t = threadIdx.x;
  int lane = t & 63, wid = t >> 6;
  int wave = blockIdx.x * (blockDim.x >> 6) + wid;
  int nw = gridDim.x * (blockDim.x >> 6);
  float wg = Wg[lane], bgv = bgp[0];

  for (int node = wave; node < n; node += nw) {
    int beg = row_start[node], end = row_start[node + 1];
    float a0 = 0.f, a1 = 0.f, a2 = 0.f, a3 = 0.f;
    for (int base = beg; base < end; base += 64) {
      int2 ev = make_int2(0, 0);
      if (base + lane < end) ev = csr[base + lane];
      int cnt = end - base; if (cnt > 64) cnt = 64;
      int j = 0;
      for (; j + 4 <= cnt; j += 4) {
        int   s0 = __shfl(ev.x, j + 0, 64), s1 = __shfl(ev.x, j + 1, 64);
        int   s2 = __shfl(ev.x, j + 2, 64), s3 = __shfl(ev.x, j + 3, 64);
        float w0 = __int_as_float(__shfl(ev.y, j + 0, 64));
        float w1 = __int_as_float(__shfl(ev.y, j + 1, 64));
        float w2 = __int_as_float(__shfl(ev.y, j + 2, 64));
        float w3 = __int_as_float(__shfl(ev.y, j + 3, 64));
        a0 += w0 * h2f(x[(unsigned)(s0 * C) + lane]);
        a1 += w1 * h2f(x[(unsigned)(s1 * C) + lane]);
        a2 += w2 * h2f(x[(unsigned)(s2 * C) + lane]);
        a3 += w3 * h2f(x[(unsigned)(s3 * C) + lane]);
      }
      for (; j < cnt; ++j) {
        int sj = __shfl(ev.x, j, 64);
        float wj = __int_as_float(__shfl(ev.y, j, 64));
        a0 += wj * h2f(x[(unsigned)(sj * C) + lane]);
      }
    }
    float acc = (a0 + a1) + (a2 + a3);
    float p = acc * wg;
#pragma unroll
    for (int off = 32; off > 0; off >>= 1) p += __shfl_xor(p, off, 64);
    float g = 1.f / (1.f + expf(-(p * s_in + bgv)));
    size_t o = (size_t)node * C + lane;
    x_next[o] = f2h(acc * 0.0625f);
    out[o] += g * (acc * s_in);
  }
}

// ---------------------------------------------------------------------------
extern "C" void kernel_launch(void* const* d_in, const int* in_sizes, int n_in,
                              void* d_out, int out_size, void* d_ws, size_t ws_size,
                              hipStream_t stream) {
  const float* nf   = (const float*)d_in[0];
  const float* ew   = (const float*)d_in[1];
  const float* W1   = (const float*)d_in[2];
  const float* b1   = (const float*)d_in[3];
  const float* W2   = (const float*)d_in[4];
  const float* b2   = (const float*)d_in[5];
  const float* Wg   = (const float*)d_in[6];
  const float* bg   = (const float*)d_in[7];
  const int* send   = (const int*)d_in[8];
  const int* recv   = (const int*)d_in[9];
  float* out = (float*)d_out;

  int n = in_sizes[0] / F_IN;     // 100000
  int E = in_sizes[1];            // 3200000
  const int K = 20;
  int NB = (n + BMASK) >> BSHIFT; // 196 buckets

  size_t slotElems = (size_t)n * C;          // ushorts per slot
  // deferred layout: hbuf fp32 | slots[(K+1)] fp16 | csr int2 | row_start |
  // cursor | gcur.  ibuf aliases slots[1..2] (25.6MB, free until hop 1).
  size_t need = slotElems * 4                      // hbuf
              + (size_t)(K + 1) * slotElems * 2    // slots
              + (size_t)E * 8                      // csr
              + (size_t)(2 * n + 1 + NB) * 4;      // row_start + cursor + gcur

  if (ws_size >= need && E * 2 <= (int)(K * slotElems / 4)) {
    // ---------------- deferred-gate path (binned CSR build) ----------------
    float*  hbuf = (float*)d_ws;
    ushort* slots = (ushort*)(hbuf + slotElems);
    int2*   csr  = (int2*)(slots + (size_t)(K + 1) * slotElems);
    int* row_start = (int*)(csr + E);
    int* cursor    = row_start + (n + 1);
    int* gcur      = cursor + n;
    int2* ibuf     = (int2*)(slots + slotElems);   // aliases slots 1..2

    gemm1_relu<<<(n + 63) / 64, 256, 0, stream>>>(nf, W1, b1, hbuf, n);
    gemm2_gate<<<(n + 3) / 4, 256, 0, stream>>>(hbuf, W2, b2, Wg, bg,
                                                slots, out, n, /*write_out=*/0);

    zero_int<<<(n + 255) / 256, 256, 0, stream>>>(cursor, n);
    hist_recv<<<(E + 255) / 256, 256, 0, stream>>>(recv, cursor, E);
    scan_counts<<<1, 1024, 0, stream>>>(cursor, row_start, n);
    init_gcur<<<(NB + 255) / 256, 256, 0, stream>>>(row_start, gcur, NB);
    bin_edges<<<(E + CHUNK - 1) / CHUNK, 256, 0, stream>>>(send, recv, ew,
                                                           gcur, ibuf, E, NB);
    scatter_bucket<<<NB, 256, 0, stream>>>(ibuf, row_start, csr, n);

    for (int k = 0; k < K; ++k) {
      spmm_pair<<<(n + 3) / 4, 256, 0, stream>>>(
          slots + (size_t)k * slotElems, row_start, csr,
          slots + (size_t)(k + 1) * slotElems, n);
    }
    gate_sum<<<(n + 3) / 4, 256, 0, stream>>>(slots, Wg, bg, out, n, K + 1,
                                              slotElems);
  } else {
    // ---------------- fallback: round-5 fused path ----------------
    float*  hbuf = (float*)d_ws;
    ushort* xA   = (ushort*)(hbuf + slotElems);
    ushort* xB   = xA + slotElems;
    int2*   csr  = (int2*)(xB + slotElems);
    int* row_start = (int*)(csr + E);
    int* cursor    = row_start + (n + 1);

    gemm1_relu<<<(n + 63) / 64, 256, 0, stream>>>(nf, W1, b1, hbuf, n);
    gemm2_gate<<<(n + 3) / 4, 256, 0, stream>>>(hbuf, W2, b2, Wg, bg,
                                                xA, out, n, /*write_out=*/1);

    zero_int<<<(n + 255) / 256, 256, 0, stream>>>(cursor, n);
    hist_recv<<<(E + 255) / 256, 256, 0, stream>>>(recv, cursor, E);
    scan_counts<<<1, 1024, 0, stream>>>(cursor, row_start, n);
    scatter_edges<<<(E + 255) / 256, 256, 0, stream>>>(send, recv, ew, cursor,
                                                       csr, E);

    ushort* xin = xA;
    ushort* xout = xB;
    for (int k = 0; k < K; ++k) {
      float s_in = ldexpf(1.0f, 4 * k);   // 16^k, exact
      spmm_gate<<<(n + 3) / 4, 256, 0, stream>>>(xin, row_start, csr, Wg, bg,
                                                 xout, out, n, s_in);
      ushort* tmp = xin; xin = xout; xout = tmp;
    }
  }
}